// Round 8
// baseline (417.868 us; speedup 1.0000x reference)
//
#include <hip/hip_runtime.h>

typedef short bf8 __attribute__((ext_vector_type(8)));
typedef float f32x4 __attribute__((ext_vector_type(4)));

static __device__ __forceinline__ unsigned short f2bf(float f) {
  unsigned u = __float_as_uint(f);
  unsigned r = u + 0x7FFFu + ((u >> 16) & 1u);
  return (unsigned short)(r >> 16);
}
static __device__ __forceinline__ float bf2f(unsigned short h) {
  return __uint_as_float(((unsigned)h) << 16);
}
// order-preserving float<->u32 key (for LDS atomicMax only)
static __device__ __forceinline__ unsigned fkey(float f) {
  unsigned u = __float_as_uint(f);
  return (u & 0x80000000u) ? ~u : (u | 0x80000000u);
}
static __device__ __forceinline__ float kdec(unsigned k) {
  unsigned u = (k & 0x80000000u) ? (k & 0x7FFFFFFFu) : ~k;
  return __uint_as_float(u);
}

// async global->LDS, 16B per lane. lds dest: wave-uniform base + lane*16.
static __device__ __forceinline__ void gload_lds16(const unsigned short* g, unsigned short* l) {
  __builtin_amdgcn_global_load_lds((const __attribute__((address_space(1))) void*)g,
                                   (__attribute__((address_space(3))) void*)l, 16, 0, 0);
}

// unfold(k=3,pad=1,stride=1) value: row d = (cc*3+ki)*3+kj, col m = i*S+j, src [C][S][S]
static __device__ __forceinline__ float uf3(const float* __restrict__ src, int lgS, int d, int m) {
  const int S = 1 << lgS;
  int cc = d / 9;
  int r9 = d - cc * 9;
  int ki = r9 / 3;
  int kj = r9 - ki * 3;
  int i = (m >> lgS) + ki - 1;
  int j = (m & (S - 1)) + kj - 1;
  if ((unsigned)i >= (unsigned)S || (unsigned)j >= (unsigned)S) return 0.f;
  return src[((size_t)cc << (2 * lgS)) + ((size_t)i << lgS) + j];
}

// ---------------- prep kernels (fused) ----------------

// blocks [0,1024): colnorm+bias-dots of lrsr3 -> sclr, bl2, bl1. blocks [1024,2048): colnorm of rsr3 -> scu3.
__global__ __launch_bounds__(256) void k_colnorm2(const float* __restrict__ lrsr3, const float* __restrict__ rsr3,
                                                  const float* __restrict__ b1, const float* __restrict__ b2,
                                                  float* __restrict__ sclr, float* __restrict__ scu3,
                                                  float* __restrict__ bl2, float* __restrict__ bl1) {
  const bool lr = blockIdx.x < 1024;
  const int m = blockIdx.x & 1023;
  const float* src = lr ? lrsr3 : rsr3;
  float s = 0.f, d1 = 0.f, d2 = 0.f;
  for (int d = threadIdx.x; d < 2304; d += 256) {
    float v = uf3(src, 5, d, m);
    s += v * v; d1 += b1[d] * v; d2 += b2[d] * v;
  }
  __shared__ float r0[256], r1[256], r2[256];
  r0[threadIdx.x] = s; r1[threadIdx.x] = d1; r2[threadIdx.x] = d2;
  __syncthreads();
  for (int o = 128; o > 0; o >>= 1) {
    if (threadIdx.x < o) {
      r0[threadIdx.x] += r0[threadIdx.x + o];
      r1[threadIdx.x] += r1[threadIdx.x + o];
      r2[threadIdx.x] += r2[threadIdx.x + o];
    }
    __syncthreads();
  }
  if (threadIdx.x == 0) {
    float sc = 1.f / fmaxf(sqrtf(r0[0]), 1e-12f);
    if (lr) { sclr[m] = sc; bl2[m] = r1[0] * sc; bl1[m] = r2[0] * sc; }
    else    { scu3[m] = sc; }
  }
}

// normalized unfold, bf16, layout [m][d]
__global__ __launch_bounds__(256) void k_pass2_md_bf(const float* __restrict__ src, const float* __restrict__ scale, unsigned short* __restrict__ out) {
  int id = blockIdx.x * 256 + threadIdx.x;
  int m = id / 2304, d = id - m * 2304;
  out[id] = f2bf(uf3(src, 5, d, m) * scale[m]);
}

// fused unfolds: blocks [0,18432): rsr2 -> U2b [4096][1152]; rest: rsr1 -> U1b [16384][640] (cols 576+ zero)
__global__ __launch_bounds__(256) void k_unfold2(const float* __restrict__ rsr2, const float* __restrict__ rsr1,
                                                 unsigned short* __restrict__ U2b, unsigned short* __restrict__ U1b) {
  int bid = blockIdx.x;
  if (bid < 18432) {
    int id = bid * 256 + threadIdx.x;
    int n = id / 1152, c = id - n * 1152;
    U2b[id] = f2bf(uf3(rsr2, 6, c, n));
  } else {
    int id = (bid - 18432) * 256 + threadIdx.x;
    int n = id / 640, c = id - n * 640;
    float v = (c < 576) ? uf3(rsr1, 7, c, n) : 0.f;
    U1b[id] = f2bf(v);
  }
}

// fused W transposes, LDS-tiled 64x64: blocks x<18 -> W1 (Cw=1152), else W2 (Cw=576)
__global__ __launch_bounds__(256) void k_wtrans2(const float* __restrict__ W1, const float* __restrict__ W2,
                                                 unsigned short* __restrict__ W1t, unsigned short* __restrict__ W2t) {
  __shared__ unsigned short Ls[64][65];
  const float* W; unsigned short* Wt; int Cw, c0;
  if (blockIdx.x < 18) { W = W1; Wt = W1t; Cw = 1152; c0 = blockIdx.x * 64; }
  else                 { W = W2; Wt = W2t; Cw = 576;  c0 = (blockIdx.x - 18) * 64; }
  const int d0 = blockIdx.y * 64;
#pragma unroll
  for (int i = 0; i < 16; ++i) {
    int idx = threadIdx.x + i * 256;
    int r = idx >> 6, c = idx & 63;
    Ls[r][c] = f2bf(W[(size_t)(d0 + r) * Cw + c0 + c]);
  }
  __syncthreads();
#pragma unroll
  for (int i = 0; i < 16; ++i) {
    int idx = threadIdx.x + i * 256;
    int cc = idx >> 6, rr = idx & 63;
    Wt[(size_t)(c0 + cc) * 2304 + d0 + rr] = Ls[rr][cc];
  }
}

// fused bw dots + bb: grid (8,10). y<9: x<5 -> bw2 chunk, x in [5,8) -> bw1 chunk. y==9: x==0 -> bb[0], x==1 -> bb[1].
__global__ __launch_bounds__(256) void k_bwbb(const float* __restrict__ W1, const float* __restrict__ W2,
                                              const float* __restrict__ b1, const float* __restrict__ b2,
                                              float* __restrict__ bw2, float* __restrict__ bw1,
                                              float* __restrict__ bb) {
  if (blockIdx.y == 9) {
    if (blockIdx.x >= 2) return;
    const float* b = blockIdx.x ? b2 : b1;
    float s = 0.f;
    for (int d = threadIdx.x; d < 2304; d += 256) s += b[d] * b[d];
    __shared__ float red[256];
    red[threadIdx.x] = s; __syncthreads();
    for (int o = 128; o > 0; o >>= 1) { if (threadIdx.x < o) red[threadIdx.x] += red[threadIdx.x + o]; __syncthreads(); }
    if (threadIdx.x == 0) bb[blockIdx.x] = red[0];
    return;
  }
  const bool two = blockIdx.x < 5;
  const float* W = two ? W1 : W2;
  const float* b = two ? b1 : b2;
  float* bw = two ? bw2 : bw1;
  const int Cw = two ? 1152 : 576;
  int c = (two ? blockIdx.x : blockIdx.x - 5) * 256 + threadIdx.x;
  if (c >= Cw) return;
  int d0 = blockIdx.y * 256;
  float s = 0.f;
  for (int d = d0; d < d0 + 256; ++d) s += b[d] * W[(size_t)d * Cw + c];
  atomicAdd(&bw[c], s);
}

// ---------------- bf16 MFMA GEMM body: 128x128 tile, BK=64, 4 waves, counted-vmcnt, XCD-chunked ----------------
// TN: C[i][j] = sum_k A[i][k]*Bt[j][k].  Two jobs per dispatch (logical id < nb0 -> j0).
// EPI 0: store bf16 C (row-split Clo/Chi at Msplit)
// EPI 1: per-(colblock,wave-half) partials (UNIQUE writer per slot = bx*2+wc):
//        pnsq[bx*2+wc][i] = sum_{j in 64-col half} C[i][j]*A[i][j]; pbwd likewise with bw[j]*A[i][j]
// EPI 2: ninv[i] from summed partials (npart = 2*nbx_E1), cmax[by][j] = max_{i in blk} (C[i][j]+bl[j])*ninv[i]
struct Job {
  const unsigned short* Alo;
  const unsigned short* Ahi;
  const unsigned short* Bt;
  unsigned short* Clo;
  unsigned short* Chi;
  const float* bl;
  const float* bb;
  const float* bw;
  const float* pnsq_in;
  const float* pbwd_in;
  float* pnsq;
  float* pbwd;
  float* cmax;
  int Msplit, N, K, nbx, which, Mtot, npart;
};

template <int EPI, int NBUF>
static __device__ __forceinline__ void gemm_body(const Job& j0, const Job& j1, int nb0) {
  __shared__ __align__(16) unsigned short As[NBUF][128 * 64];
  __shared__ __align__(16) unsigned short Bs[NBUF][128 * 64];
  __shared__ unsigned colkey[128];

  // bijective XCD-chunked swizzle (m204)
  const int nwg = (int)gridDim.x;
  const int h = (int)blockIdx.x;
  const int qq = nwg >> 3, rm = nwg & 7;
  const int xcd = h & 7, wth = h >> 3;
  const int bid = (xcd < rm ? xcd * (qq + 1) : rm * (qq + 1) + (xcd - rm) * qq) + wth;

  const bool first = (bid < nb0);
  const Job j = first ? j0 : j1;
  const int local = bid - (first ? 0 : nb0);
  const int by = local / j.nbx;
  const int bx = local - by * j.nbx;
  const int m0 = by * 128, n0 = bx * 128;
  const int K = j.K, N = j.N;

  const unsigned short* Abase = (m0 < j.Msplit)
      ? j.Alo + (size_t)m0 * K
      : j.Ahi + (size_t)(m0 - j.Msplit) * K;

  const int tid = threadIdx.x;
  const int l = tid & 63;
  const int w = tid >> 6;
  const int wr = w >> 1, wc = w & 1;
  if (EPI == 2 && tid < 128) colkey[tid] = 0u;

  f32x4 acc[4][4] = {};

  const int srow = w * 32;
  const int lrow = l >> 3;
  const int gcol = ((l & 7) ^ lrow) * 8;   // pre-swizzled global column
  const int mr = l & 15;
  const int kg = l >> 4;

  const int nt = K >> 6;
  const int snap_kb = n0 + wc * 64;
  unsigned short snap[4][4][4];

  auto stage = [&](int buf, int kb) {
#pragma unroll
    for (int i = 0; i < 4; ++i) {
      int r = srow + i * 8;
      gload_lds16(Abase + (size_t)(r + lrow) * K + kb + gcol, &As[buf][r * 64]);
      gload_lds16(j.Bt + (size_t)(n0 + r + lrow) * K + kb + gcol, &Bs[buf][r * 64]);
    }
  };
  auto waitv = [&](int W) {
    if (W >= 2)      asm volatile("s_waitcnt vmcnt(16)\ns_barrier" ::: "memory");
    else if (W == 1) asm volatile("s_waitcnt vmcnt(8)\ns_barrier" ::: "memory");
    else             asm volatile("s_waitcnt vmcnt(0)\ns_barrier" ::: "memory");
  };

  // prologue: up to NBUF tiles in flight; ensure tile 0 landed
#pragma unroll
  for (int p = 0; p < NBUF; ++p) if (p < nt) stage(p, p << 6);
  { int inflight = (NBUF < nt ? NBUF : nt); waitv(inflight - 1); }

  int cur = 0;
  for (int t = 0; t < nt; ++t) {
#pragma unroll
    for (int ks = 0; ks < 2; ++ks) {
      bf8 af[4], bv[4];
#pragma unroll
      for (int mi = 0; mi < 4; ++mi) {
        const int row = wr * 64 + mi * 16 + mr;
        af[mi] = *(const bf8*)&As[cur][row * 64 + (((ks * 4 + kg) ^ (row & 7)) * 8)];
      }
#pragma unroll
      for (int ni = 0; ni < 4; ++ni) {
        const int row = wc * 64 + ni * 16 + mr;
        bv[ni] = *(const bf8*)&Bs[cur][row * 64 + (((ks * 4 + kg) ^ (row & 7)) * 8)];
      }
      __builtin_amdgcn_s_setprio(1);
#pragma unroll
      for (int mi = 0; mi < 4; ++mi)
#pragma unroll
        for (int ni = 0; ni < 4; ++ni)
          acc[mi][ni] = __builtin_amdgcn_mfma_f32_16x16x32_bf16(af[mi], bv[ni], acc[mi][ni], 0, 0, 0);
      __builtin_amdgcn_s_setprio(0);
    }
    if (EPI == 1 && (t << 6) == snap_kb) {
#pragma unroll
      for (int mi = 0; mi < 4; ++mi)
#pragma unroll
        for (int e = 0; e < 4; ++e) {
          const int row = wr * 64 + mi * 16 + kg * 4 + e;
#pragma unroll
          for (int ni = 0; ni < 4; ++ni) {
            const int slot = ni * 2 + (mr >> 3);
            snap[mi][ni][e] = As[cur][row * 64 + ((slot ^ (row & 7)) * 8) + (mr & 7)];
          }
        }
    }
    if (t + 1 < nt) {
      asm volatile("s_waitcnt lgkmcnt(0)\ns_barrier" ::: "memory");   // buf[cur] free everywhere
      if (t + NBUF < nt) stage(cur, (t + NBUF) << 6);                 // refill freed buffer
      int remain = nt - t - 1;                                        // tiles still needed
      int W = (NBUF < remain ? NBUF : remain) - 1;                    // outstanding allowed after wait
      waitv(W);                                                       // tile t+1 landed
      cur = (cur + 1 == NBUF) ? 0 : cur + 1;
    }
  }

  // C/D frag layout: col = mr, row = kg*4 + e (within 16x16)
  const int lr0 = wr * 64;
  const int lc0 = wc * 64;
  if (EPI == 0) {
    unsigned short* Cbase = (m0 < j.Msplit)
        ? j.Clo + (size_t)m0 * N
        : j.Chi + (size_t)(m0 - j.Msplit) * N;
#pragma unroll
    for (int mi = 0; mi < 4; ++mi)
#pragma unroll
      for (int ni = 0; ni < 4; ++ni)
#pragma unroll
        for (int e = 0; e < 4; ++e)
          Cbase[(size_t)(lr0 + mi * 16 + kg * 4 + e) * (size_t)N + (n0 + lc0 + ni * 16 + mr)] = f2bf(acc[mi][ni][e]);
  } else if (EPI == 1) {
    float rp[4][4] = {};
    float bp[4][4] = {};
#pragma unroll
    for (int ni = 0; ni < 4; ++ni) {
      const float bwv = j.bw[n0 + lc0 + ni * 16 + mr];
#pragma unroll
      for (int mi = 0; mi < 4; ++mi)
#pragma unroll
        for (int e = 0; e < 4; ++e) {
          const float av = bf2f(snap[mi][ni][e]);
          rp[mi][e] += acc[mi][ni][e] * av;
          bp[mi][e] += bwv * av;
        }
    }
#pragma unroll
    for (int off = 1; off < 16; off <<= 1)
#pragma unroll
      for (int mi = 0; mi < 4; ++mi)
#pragma unroll
        for (int e = 0; e < 4; ++e) {
          rp[mi][e] += __shfl_xor(rp[mi][e], off);
          bp[mi][e] += __shfl_xor(bp[mi][e], off);
        }
    if (mr == 0) {
      // UNIQUE writer per (column-half slot = bx*2+wc, row). Waves (wr,0)/(wr,1) cover the
      // same rows but different 64-col halves -> separate slots (round-7 race fix).
      const size_t slotbase = (size_t)(bx * 2 + wc) * j.Mtot;
#pragma unroll
      for (int mi = 0; mi < 4; ++mi)
#pragma unroll
        for (int e = 0; e < 4; ++e) {
          const int r = m0 + lr0 + mi * 16 + kg * 4 + e;
          j.pnsq[slotbase + r] = rp[mi][e];
          j.pbwd[slotbase + r] = bp[mi][e];
        }
    }
  } else {
    const float bbv = j.bb[j.which];
    float nv[4][4];
#pragma unroll
    for (int mi = 0; mi < 4; ++mi)
#pragma unroll
      for (int e = 0; e < 4; ++e) {
        const int r = m0 + lr0 + mi * 16 + kg * 4 + e;
        float nsq = 0.f, bwd = 0.f;
        for (int p = 0; p < j.npart; ++p) {
          nsq += j.pnsq_in[(size_t)p * j.Mtot + r];
          bwd += j.pbwd_in[(size_t)p * j.Mtot + r];
        }
        float tq = nsq + 2.f * bwd + bbv;
        nv[mi][e] = 1.f / fmaxf(sqrtf(fmaxf(tq, 0.f)), 1e-12f);
      }
#pragma unroll
    for (int ni = 0; ni < 4; ++ni) {
      float blv = j.bl[n0 + lc0 + ni * 16 + mr];
      float mx = -3.0e38f;
#pragma unroll
      for (int mi = 0; mi < 4; ++mi)
#pragma unroll
        for (int e = 0; e < 4; ++e) mx = fmaxf(mx, (acc[mi][ni][e] + blv) * nv[mi][e]);
      atomicMax(&colkey[lc0 + ni * 16 + mr], fkey(mx));   // LDS atomic only
    }
    __syncthreads();
    if (tid < 128) j.cmax[(size_t)by * 1024 + n0 + tid] = kdec(colkey[tid]);  // unique writer
  }
}

__global__ __launch_bounds__(256) void k_gP (Job a, Job b, int nb0) { gemm_body<0, 3>(a, b, nb0); }
__global__ __launch_bounds__(256) void k_gE1(Job a, Job b, int nb0) { gemm_body<1, 2>(a, b, nb0); }
__global__ __launch_bounds__(256) void k_gE2(Job a, Job b, int nb0) { gemm_body<2, 2>(a, b, nb0); }

// ---------------- fp32 pixel Gram: G2[m][n] = sum_c L[c][m]*R[c][n], 1024x1024, K=256 ----------------
__global__ __launch_bounds__(256) void k_pixgram(const float* __restrict__ L, const float* __restrict__ R,
                                                 float* __restrict__ G2) {
  __shared__ float As[16][32];
  __shared__ float Bs[16][32];
  const int tid = threadIdx.x;
  const int tx = tid & 15, ty = tid >> 4;
  const int m0 = blockIdx.y * 32, n0 = blockIdx.x * 32;
  float acc[2][2] = {};
  for (int kb = 0; kb < 256; kb += 16) {
    __syncthreads();
    {
      int kk = tid >> 5, mm = tid & 31;
      As[kk][mm] = L[(size_t)(kb + kk) * 1024 + m0 + mm];
      Bs[kk][mm] = R[(size_t)(kb + kk) * 1024 + n0 + mm];
      int e2 = tid + 256; int kk2 = e2 >> 5, mm2 = e2 & 31;
      As[kk2][mm2] = L[(size_t)(kb + kk2) * 1024 + m0 + mm2];
      Bs[kk2][mm2] = R[(size_t)(kb + kk2) * 1024 + n0 + mm2];
    }
    __syncthreads();
#pragma unroll
    for (int kk = 0; kk < 16; ++kk) {
      float a0 = As[kk][ty * 2], a1 = As[kk][ty * 2 + 1];
      float b0 = Bs[kk][tx * 2], b1 = Bs[kk][tx * 2 + 1];
      acc[0][0] = fmaf(a0, b0, acc[0][0]); acc[0][1] = fmaf(a0, b1, acc[0][1]);
      acc[1][0] = fmaf(a1, b0, acc[1][0]); acc[1][1] = fmaf(a1, b1, acc[1][1]);
    }
  }
#pragma unroll
  for (int i = 0; i < 2; ++i)
#pragma unroll
    for (int j = 0; j < 2; ++j)
      G2[(size_t)(m0 + ty * 2 + i) * 1024 + (n0 + tx * 2 + j)] = acc[i][j];
}

// ---------------- R3 max/argmax from pixel Gram via masked 9-point diagonal-shift sum ----------------
__global__ __launch_bounds__(256) void k_r3max(const float* __restrict__ G2, const float* __restrict__ scu3,
                                               const float* __restrict__ sclr,
                                               float* __restrict__ s3, int* __restrict__ arg) {
  const int m = blockIdx.x;
  const int mi = m >> 5, mj = m & 31;
  float best = -3.0e38f; int bi = 0;
  for (int n = threadIdx.x; n < 1024; n += 256) {
    const int ni = n >> 5, nj = n & 31;
    float raw = 0.f;
#pragma unroll
    for (int dy = -1; dy <= 1; ++dy) {
#pragma unroll
      for (int dx = -1; dx <= 1; ++dx) {
        bool vm = ((unsigned)(mi + dy) < 32u) && ((unsigned)(mj + dx) < 32u);
        bool vn = ((unsigned)(ni + dy) < 32u) && ((unsigned)(nj + dx) < 32u);
        if (vm && vn) {
          int off = dy * 32 + dx;
          raw += G2[(size_t)(m + off) * 1024 + (n + off)];
        }
      }
    }
    float v = raw * scu3[n];
    if (v > best) { best = v; bi = n; }
  }
  __shared__ float bv[256]; __shared__ int bidx[256];
  bv[threadIdx.x] = best; bidx[threadIdx.x] = bi;
  __syncthreads();
  for (int o = 128; o > 0; o >>= 1) {
    if (threadIdx.x < o) {
      float ov = bv[threadIdx.x + o]; int oi = bidx[threadIdx.x + o];
      if (ov > bv[threadIdx.x] || (ov == bv[threadIdx.x] && oi < bidx[threadIdx.x])) {
        bv[threadIdx.x] = ov; bidx[threadIdx.x] = oi;
      }
    }
    __syncthreads();
  }
  if (threadIdx.x == 0) { s3[m] = bv[0] * sclr[m]; arg[m] = bidx[0]; }
}

// ---------------- fused gather+fold + S1/S2 finalize ----------------
// blocks [0,1024): T3; [1024,3072): T2; [3072,7168): T1; [7168,7176): S1/S2 reduce from cmax
__global__ __launch_bounds__(256) void k_tfold(const float* __restrict__ ref3, const float* __restrict__ ref2,
                                               const float* __restrict__ ref1, const int* __restrict__ arg,
                                               const float* __restrict__ cmax1, const float* __restrict__ cmax2,
                                               float* __restrict__ out) {
  int bid = blockIdx.x;
  if (bid < 1024) {
    int id = bid * 256 + threadIdx.x;
    int c = id >> 10, rem = id & 1023;
    int y = rem >> 5, x = rem & 31;
    float s = 0.f;
#pragma unroll
    for (int ki = 0; ki < 3; ++ki) {
      int i = y + 1 - ki;
      if ((unsigned)i >= 32u) continue;
#pragma unroll
      for (int kj = 0; kj < 3; ++kj) {
        int j = x + 1 - kj;
        if ((unsigned)j >= 32u) continue;
        int n2 = arg[i * 32 + j];
        int rr = (n2 >> 5) + ki - 1, cc = (n2 & 31) + kj - 1;
        if ((unsigned)rr < 32u && (unsigned)cc < 32u) s += ref3[(size_t)c * 1024 + rr * 32 + cc];
      }
    }
    out[3072 + id] = s * (1.f / 9.f);
  } else if (bid < 3072) {
    int id = (bid - 1024) * 256 + threadIdx.x;
    int c = id >> 12, rem = id & 4095;
    int y = rem >> 6, x = rem & 63;
    float s = 0.f;
#pragma unroll
    for (int ki = 0; ki < 6; ++ki) {
      int t = y + 2 - ki;
      if (t < 0 || (t & 1)) continue;
      int i = t >> 1;
      if (i >= 32) continue;
#pragma unroll
      for (int kj = 0; kj < 6; ++kj) {
        int t2 = x + 2 - kj;
        if (t2 < 0 || (t2 & 1)) continue;
        int j = t2 >> 1;
        if (j >= 32) continue;
        int n2 = arg[i * 32 + j];
        int rr = (n2 >> 5) * 2 + ki - 2, cc = (n2 & 31) * 2 + kj - 2;
        if ((unsigned)rr < 64u && (unsigned)cc < 64u) s += ref2[(size_t)c * 4096 + rr * 64 + cc];
      }
    }
    out[265216 + id] = s * (1.f / 9.f);
  } else if (bid < 7168) {
    int id = (bid - 3072) * 256 + threadIdx.x;
    int c = id >> 14, rem = id & 16383;
    int y = rem >> 7, x = rem & 127;
    float s = 0.f;
#pragma unroll
    for (int ki = 0; ki < 12; ++ki) {
      int t = y + 4 - ki;
      if (t < 0 || (t & 3)) continue;
      int i = t >> 2;
      if (i >= 32) continue;
#pragma unroll
      for (int kj = 0; kj < 12; ++kj) {
        int t2 = x + 4 - kj;
        if (t2 < 0 || (t2 & 3)) continue;
        int j = t2 >> 2;
        if (j >= 32) continue;
        int n2 = arg[i * 32 + j];
        int rr = (n2 >> 5) * 4 + ki - 4, cc = (n2 & 31) * 4 + kj - 4;
        if ((unsigned)rr < 128u && (unsigned)cc < 128u) s += ref1[(size_t)c * 16384 + rr * 128 + cc];
      }
    }
    out[789504 + id] = s * (1.f / 9.f);
  } else {
    int t = (bid - 7168) * 256 + threadIdx.x;  // 0..2047
    if (t < 1024) {
      float mx = -3.0e38f;
      for (int rb = 0; rb < 128; ++rb) mx = fmaxf(mx, cmax1[rb * 1024 + t]);
      out[t] = mx;            // S_1
    } else {
      int tt = t - 1024;
      float mx = -3.0e38f;
      for (int rb = 0; rb < 32; ++rb) mx = fmaxf(mx, cmax2[rb * 1024 + tt]);
      out[1024 + tt] = mx;    // S_2
    }
  }
}

// ---------------- workspace layout (bytes) ----------------
// zero-initialized (memset each launch): bw accumulators only
static constexpr size_t OFF_BW2     = 0;                        // 1152 f32
static constexpr size_t OFF_BW1     = 4608;                     // 640 f32
static constexpr size_t ZERO_BYTES  = 7168;
// non-zeroed (all cells uniquely written before read):
static constexpr size_t OFF_BB      = 7168;                     // 2 f32 (pad to 256)
static constexpr size_t OFF_BL2     = 7424;                     // 1024 f32
static constexpr size_t OFF_BL1     = 11520;                    // 1024 f32
static constexpr size_t OFF_SCLR    = 15616;                    // 1024 f32
static constexpr size_t OFF_SCU3    = 19712;                    // 1024 f32
static constexpr size_t OFF_R3ARG   = 23808;                    // 1024 int
static constexpr size_t OFF_PNSQ2   = 27904;                    // f32 [18][4096]
static constexpr size_t OFF_PBWD2   = OFF_PNSQ2 + 294912;       // f32 [18][4096]
static constexpr size_t OFF_PNSQ1   = OFF_PBWD2 + 294912;       // f32 [10][16384]
static constexpr size_t OFF_PBWD1   = OFF_PNSQ1 + 655360;       // f32 [10][16384]
static constexpr size_t OFF_CMAX2   = OFF_PBWD1 + 655360;       // f32 [32][1024]
static constexpr size_t OFF_CMAX1   = OFF_CMAX2 + 131072;       // f32 [128][1024]
static constexpr size_t OFF_LR3NBT  = OFF_CMAX1 + 524288;       // bf16 [1024][2304]
static constexpr size_t OFF_U2B     = OFF_LR3NBT + 4718592;     // bf16 [4096][1152]
static constexpr size_t OFF_U1B     = OFF_U2B    + 9437184;     // bf16 [16384][640]
static constexpr size_t OFF_W1T     = OFF_U1B    + 20971520;    // bf16 [1152][2304]
static constexpr size_t OFF_W2T     = OFF_W1T    + 5308416;     // bf16 [640][2304] (rows 576+ zero)
static constexpr size_t OFF_A2      = OFF_W2T    + 2949120;     // bf16 [1152][1152]
static constexpr size_t OFF_A1      = OFF_A2     + 2654208;     // bf16 [640][640]
static constexpr size_t OFF_M2T     = OFF_A1     + 819200;      // bf16 [1024][1152]
static constexpr size_t OFF_M1T     = OFF_M2T    + 2359296;     // bf16 [1024][640]
static constexpr size_t OFF_G2      = OFF_M1T    + 1310720;     // f32 [1024][1024]

extern "C" void kernel_launch(void* const* d_in, const int* in_sizes, int n_in,
                              void* d_out, int out_size, void* d_ws, size_t ws_size,
                              hipStream_t stream) {
  (void)in_sizes; (void)n_in; (void)out_size; (void)ws_size;
  const float* lrsr3  = (const float*)d_in[0];
  const float* rsr1   = (const float*)d_in[1];
  const float* rsr2   = (const float*)d_in[2];
  const float* rsr3   = (const float*)d_in[3];
  const float* ref1   = (const float*)d_in[4];
  const float* ref2   = (const float*)d_in[5];
  const float* ref3   = (const float*)d_in[6];
  const float* W1     = (const float*)d_in[7];
  const float* b1     = (const float*)d_in[8];
  const float* W2     = (const float*)d_in[9];
  const float* b2     = (const float*)d_in[10];
  float* out = (float*)d_out;
  char* ws = (char*)d_ws;

  float*          bw2     = (float*)(ws + OFF_BW2);
  float*          bw1     = (float*)(ws + OFF_BW1);
  float*          bb      = (float*)(ws + OFF_BB);
  float*          bl2     = (float*)(ws + OFF_BL2);
  float*          bl1     = (float*)(ws + OFF_BL1);
  float*          sclr    = (float*)(ws + OFF_SCLR);
  float*          scu3    = (float*)(ws + OFF_SCU3);
  int*            R3arg   = (int*)(ws + OFF_R3ARG);
  float*          pnsq2   = (float*)(ws + OFF_PNSQ2);
  float*          pbwd2   = (float*)(ws + OFF_PBWD2);
  float*          pnsq1   = (float*)(ws + OFF_PNSQ1);
  float*          pbwd1   = (float*)(ws + OFF_PBWD1);
  float*          cmax2   = (float*)(ws + OFF_CMAX2);
  float*          cmax1   = (float*)(ws + OFF_CMAX1);
  unsigned short* lr3nbT  = (unsigned short*)(ws + OFF_LR3NBT);
  unsigned short* U2b     = (unsigned short*)(ws + OFF_U2B);
  unsigned short* U1b     = (unsigned short*)(ws + OFF_U1B);
  unsigned short* W1t     = (unsigned short*)(ws + OFF_W1T);
  unsigned short* W2t     = (unsigned short*)(ws + OFF_W2T);
  unsigned short* A2b     = (unsigned short*)(ws + OFF_A2);
  unsigned short* A1b     = (unsigned short*)(ws + OFF_A1);
  unsigned short* M2tb    = (unsigned short*)(ws + OFF_M2T);
  unsigned short* M1tb    = (unsigned short*)(ws + OFF_M1T);
  float*          G2      = (float*)(ws + OFF_G2);

  hipMemsetAsync(d_ws, 0, ZERO_BYTES, stream);
  // zero pad rows 576..639 of W2t
  hipMemsetAsync(ws + OFF_W2T + (size_t)576 * 2304 * 2, 0, (size_t)64 * 2304 * 2, stream);

  // norms + bias dots + pixel Gram (R3 path, all fp32)
  k_colnorm2<<<2048, 256, 0, stream>>>(lrsr3, rsr3, b1, b2, sclr, scu3, bl2, bl1);
  k_pixgram<<<dim3(32, 32), 256, 0, stream>>>(lrsr3, rsr3, G2);
  k_r3max<<<1024, 256, 0, stream>>>(G2, scu3, sclr, out + 2048, R3arg);

  // unfolds / transposes for the bf16 score paths
  k_pass2_md_bf<<<9216, 256, 0, stream>>>(lrsr3, sclr, lr3nbT);
  k_unfold2<<<59392, 256, 0, stream>>>(rsr2, rsr1, U2b, U1b);
  k_wtrans2<<<dim3(27, 36), 256, 0, stream>>>(W1, W2, W1t, W2t);
  k_bwbb<<<dim3(8, 10), 256, 0, stream>>>(W1, W2, b1, b2, bw2, bw1, bb);

  Job jz = {};

  // P: Gram matrices + M^T, fused across row-concat [Wt ; lr3nbT]
  {
    Job a = jz, b = jz;
    a.Alo = W1t; a.Ahi = lr3nbT; a.Msplit = 1152; a.Bt = W1t;
    a.Clo = A2b; a.Chi = M2tb; a.N = 1152; a.K = 2304; a.nbx = 9;
    b.Alo = W2t; b.Ahi = lr3nbT; b.Msplit = 640; b.Bt = W2t;
    b.Clo = A1b; b.Chi = M1tb; b.N = 640; b.K = 2304; b.nbx = 5;
    k_gP<<<153 + 65, 256, 0, stream>>>(a, b, 153);
  }
  // E1: per-(colblock,half) norm/bw partials via Gram quadratic form (no atomics, unique writers)
  {
    Job a = jz, b = jz;
    a.Alo = U2b; a.Ahi = U2b; a.Msplit = 4096; a.Bt = A2b;
    a.bw = bw2; a.pnsq = pnsq2; a.pbwd = pbwd2; a.Mtot = 4096;
    a.N = 1152; a.K = 1152; a.nbx = 9;
    b.Alo = U1b; b.Ahi = U1b; b.Msplit = 16384; b.Bt = A1b;
    b.bw = bw1; b.pnsq = pnsq1; b.pbwd = pbwd1; b.Mtot = 16384;
    b.N = 640; b.K = 640; b.nbx = 5;
    k_gE1<<<288 + 640, 256, 0, stream>>>(a, b, 288);
  }
  // E2: score max (ninv from summed partials inline), per-rowblock col-max stores
  {
    Job a = jz, b = jz;
    a.Alo = U2b; a.Ahi = U2b; a.Msplit = 4096; a.Bt = M2tb;
    a.bl = bl2; a.bb = bb; a.which = 0;
    a.pnsq_in = pnsq2; a.pbwd_in = pbwd2; a.Mtot = 4096; a.npart = 18;
    a.cmax = cmax2; a.N = 1024; a.K = 1152; a.nbx = 8;
    b.Alo = U1b; b.Ahi = U1b; b.Msplit = 16384; b.Bt = M1tb;
    b.bl = bl1; b.bb = bb; b.which = 1;
    b.pnsq_in = pnsq1; b.pbwd_in = pbwd1; b.Mtot = 16384; b.npart = 10;
    b.cmax = cmax1; b.N = 1024; b.K = 640; b.nbx = 8;
    k_gE2<<<256 + 1024, 256, 0, stream>>>(a, b, 256);
  }

  // transfer + S1/S2 finalize (fused)
  k_tfold<<<7176, 256, 0, stream>>>(ref3, ref2, ref1, R3arg, cmax1, cmax2, out);
}

// Round 9
// 331.215 us; speedup vs baseline: 1.2616x; 1.2616x over previous
//
#include <hip/hip_runtime.h>

typedef short bf8 __attribute__((ext_vector_type(8)));
typedef float f32x4 __attribute__((ext_vector_type(4)));

static __device__ __forceinline__ unsigned short f2bf(float f) {
  unsigned u = __float_as_uint(f);
  unsigned r = u + 0x7FFFu + ((u >> 16) & 1u);
  return (unsigned short)(r >> 16);
}
static __device__ __forceinline__ float bf2f(unsigned short h) {
  return __uint_as_float(((unsigned)h) << 16);
}
// order-preserving float<->u32 key (for LDS atomicMax only)
static __device__ __forceinline__ unsigned fkey(float f) {
  unsigned u = __float_as_uint(f);
  return (u & 0x80000000u) ? ~u : (u | 0x80000000u);
}
static __device__ __forceinline__ float kdec(unsigned k) {
  unsigned u = (k & 0x80000000u) ? (k & 0x7FFFFFFFu) : ~k;
  return __uint_as_float(u);
}

// async global->LDS, 16B per lane. lds dest: wave-uniform base + lane*16.
static __device__ __forceinline__ void gload_lds16(const unsigned short* g, unsigned short* l) {
  __builtin_amdgcn_global_load_lds((const __attribute__((address_space(1))) void*)g,
                                   (__attribute__((address_space(3))) void*)l, 16, 0, 0);
}

// unfold(k=3,pad=1,stride=1) value: row d = (cc*3+ki)*3+kj, col m = i*S+j, src [C][S][S]
static __device__ __forceinline__ float uf3(const float* __restrict__ src, int lgS, int d, int m) {
  const int S = 1 << lgS;
  int cc = d / 9;
  int r9 = d - cc * 9;
  int ki = r9 / 3;
  int kj = r9 - ki * 3;
  int i = (m >> lgS) + ki - 1;
  int j = (m & (S - 1)) + kj - 1;
  if ((unsigned)i >= (unsigned)S || (unsigned)j >= (unsigned)S) return 0.f;
  return src[((size_t)cc << (2 * lgS)) + ((size_t)i << lgS) + j];
}

// ---------------- prep kernels (fused) ----------------

// blocks [0,1024): colnorm+bias-dots of lrsr3 -> sclr, bl2, bl1. blocks [1024,2048): colnorm of rsr3 -> scu3.
__global__ __launch_bounds__(256) void k_colnorm2(const float* __restrict__ lrsr3, const float* __restrict__ rsr3,
                                                  const float* __restrict__ b1, const float* __restrict__ b2,
                                                  float* __restrict__ sclr, float* __restrict__ scu3,
                                                  float* __restrict__ bl2, float* __restrict__ bl1) {
  const bool lr = blockIdx.x < 1024;
  const int m = blockIdx.x & 1023;
  const float* src = lr ? lrsr3 : rsr3;
  float s = 0.f, d1 = 0.f, d2 = 0.f;
  for (int d = threadIdx.x; d < 2304; d += 256) {
    float v = uf3(src, 5, d, m);
    s += v * v; d1 += b1[d] * v; d2 += b2[d] * v;
  }
  __shared__ float r0[256], r1[256], r2[256];
  r0[threadIdx.x] = s; r1[threadIdx.x] = d1; r2[threadIdx.x] = d2;
  __syncthreads();
  for (int o = 128; o > 0; o >>= 1) {
    if (threadIdx.x < o) {
      r0[threadIdx.x] += r0[threadIdx.x + o];
      r1[threadIdx.x] += r1[threadIdx.x + o];
      r2[threadIdx.x] += r2[threadIdx.x + o];
    }
    __syncthreads();
  }
  if (threadIdx.x == 0) {
    float sc = 1.f / fmaxf(sqrtf(r0[0]), 1e-12f);
    if (lr) { sclr[m] = sc; bl2[m] = r1[0] * sc; bl1[m] = r2[0] * sc; }
    else    { scu3[m] = sc; }
  }
}

// normalized unfold, bf16, layout [m][d]
__global__ __launch_bounds__(256) void k_pass2_md_bf(const float* __restrict__ src, const float* __restrict__ scale, unsigned short* __restrict__ out) {
  int id = blockIdx.x * 256 + threadIdx.x;
  int m = id / 2304, d = id - m * 2304;
  out[id] = f2bf(uf3(src, 5, d, m) * scale[m]);
}

// fused unfolds: blocks [0,18432): rsr2 -> U2b [4096][1152]; rest: rsr1 -> U1b [16384][640] (cols 576+ zero)
__global__ __launch_bounds__(256) void k_unfold2(const float* __restrict__ rsr2, const float* __restrict__ rsr1,
                                                 unsigned short* __restrict__ U2b, unsigned short* __restrict__ U1b) {
  int bid = blockIdx.x;
  if (bid < 18432) {
    int id = bid * 256 + threadIdx.x;
    int n = id / 1152, c = id - n * 1152;
    U2b[id] = f2bf(uf3(rsr2, 6, c, n));
  } else {
    int id = (bid - 18432) * 256 + threadIdx.x;
    int n = id / 640, c = id - n * 640;
    float v = (c < 576) ? uf3(rsr1, 7, c, n) : 0.f;
    U1b[id] = f2bf(v);
  }
}

// fused W transposes, LDS-tiled 64x64: blocks x<18 -> W1 (Cw=1152), else W2 (Cw=576)
__global__ __launch_bounds__(256) void k_wtrans2(const float* __restrict__ W1, const float* __restrict__ W2,
                                                 unsigned short* __restrict__ W1t, unsigned short* __restrict__ W2t) {
  __shared__ unsigned short Ls[64][65];
  const float* W; unsigned short* Wt; int Cw, c0;
  if (blockIdx.x < 18) { W = W1; Wt = W1t; Cw = 1152; c0 = blockIdx.x * 64; }
  else                 { W = W2; Wt = W2t; Cw = 576;  c0 = (blockIdx.x - 18) * 64; }
  const int d0 = blockIdx.y * 64;
#pragma unroll
  for (int i = 0; i < 16; ++i) {
    int idx = threadIdx.x + i * 256;
    int r = idx >> 6, c = idx & 63;
    Ls[r][c] = f2bf(W[(size_t)(d0 + r) * Cw + c0 + c]);
  }
  __syncthreads();
#pragma unroll
  for (int i = 0; i < 16; ++i) {
    int idx = threadIdx.x + i * 256;
    int cc = idx >> 6, rr = idx & 63;
    Wt[(size_t)(c0 + cc) * 2304 + d0 + rr] = Ls[rr][cc];
  }
}

// fused bw dots + bb: grid (8,10). y<9: x<5 -> bw2 chunk, x in [5,8) -> bw1 chunk. y==9: x==0 -> bb[0], x==1 -> bb[1].
__global__ __launch_bounds__(256) void k_bwbb(const float* __restrict__ W1, const float* __restrict__ W2,
                                              const float* __restrict__ b1, const float* __restrict__ b2,
                                              float* __restrict__ bw2, float* __restrict__ bw1,
                                              float* __restrict__ bb) {
  if (blockIdx.y == 9) {
    if (blockIdx.x >= 2) return;
    const float* b = blockIdx.x ? b2 : b1;
    float s = 0.f;
    for (int d = threadIdx.x; d < 2304; d += 256) s += b[d] * b[d];
    __shared__ float red[256];
    red[threadIdx.x] = s; __syncthreads();
    for (int o = 128; o > 0; o >>= 1) { if (threadIdx.x < o) red[threadIdx.x] += red[threadIdx.x + o]; __syncthreads(); }
    if (threadIdx.x == 0) bb[blockIdx.x] = red[0];
    return;
  }
  const bool two = blockIdx.x < 5;
  const float* W = two ? W1 : W2;
  const float* b = two ? b1 : b2;
  float* bw = two ? bw2 : bw1;
  const int Cw = two ? 1152 : 576;
  int c = (two ? blockIdx.x : blockIdx.x - 5) * 256 + threadIdx.x;
  if (c >= Cw) return;
  int d0 = blockIdx.y * 256;
  float s = 0.f;
  for (int d = d0; d < d0 + 256; ++d) s += b[d] * W[(size_t)d * Cw + c];
  atomicAdd(&bw[c], s);
}

// ---------------- ninv finalize: sum the E1 partials ONCE per row (round-8 lesson: don't do this in E2) ----------------
// blocks [0,16): ninv2[4096] from 18 partials. blocks [16,80): ninv1[16384] from 10 partials.
__global__ __launch_bounds__(256) void k_ninv(const float* __restrict__ pnsq2, const float* __restrict__ pbwd2,
                                              const float* __restrict__ pnsq1, const float* __restrict__ pbwd1,
                                              const float* __restrict__ bb,
                                              float* __restrict__ ninv2, float* __restrict__ ninv1) {
  int bid = blockIdx.x;
  if (bid < 16) {
    int i = bid * 256 + threadIdx.x;   // < 4096
    float nsq = 0.f, bwd = 0.f;
#pragma unroll
    for (int p = 0; p < 18; ++p) { nsq += pnsq2[p * 4096 + i]; bwd += pbwd2[p * 4096 + i]; }
    float tq = nsq + 2.f * bwd + bb[0];
    ninv2[i] = 1.f / fmaxf(sqrtf(fmaxf(tq, 0.f)), 1e-12f);
  } else {
    int i = (bid - 16) * 256 + threadIdx.x;  // < 16384
    float nsq = 0.f, bwd = 0.f;
#pragma unroll
    for (int p = 0; p < 10; ++p) { nsq += pnsq1[p * 16384 + i]; bwd += pbwd1[p * 16384 + i]; }
    float tq = nsq + 2.f * bwd + bb[1];
    ninv1[i] = 1.f / fmaxf(sqrtf(fmaxf(tq, 0.f)), 1e-12f);
  }
}

// ---------------- bf16 MFMA GEMM body: 128x128 tile, BK=64, 4 waves, counted-vmcnt, XCD-chunked ----------------
// TN: C[i][j] = sum_k A[i][k]*Bt[j][k].  Two jobs per dispatch (logical id < nb0 -> j0).
// EPI 0: store bf16 C (row-split Clo/Chi at Msplit)
// EPI 1: per-(colblock,wave-half) partials (UNIQUE writer per slot = bx*2+wc):
//        pnsq[bx*2+wc][i] = sum_{j in 64-col half} C[i][j]*A[i][j]; pbwd likewise with bw[j]*A[i][j]
// EPI 2: cmax[by][j] = max_{i in blk} (C[i][j]+bl[j])*ninv[i]   (ninv precomputed by k_ninv)
struct Job {
  const unsigned short* Alo;
  const unsigned short* Ahi;
  const unsigned short* Bt;
  unsigned short* Clo;
  unsigned short* Chi;
  const float* bl;
  const float* bw;
  const float* ninv;
  float* pnsq;
  float* pbwd;
  float* cmax;
  int Msplit, N, K, nbx, Mtot;
};

template <int EPI, int NBUF>
static __device__ __forceinline__ void gemm_body(const Job& j0, const Job& j1, int nb0) {
  __shared__ __align__(16) unsigned short As[NBUF][128 * 64];
  __shared__ __align__(16) unsigned short Bs[NBUF][128 * 64];
  __shared__ unsigned colkey[128];

  // bijective XCD-chunked swizzle (m204)
  const int nwg = (int)gridDim.x;
  const int h = (int)blockIdx.x;
  const int qq = nwg >> 3, rm = nwg & 7;
  const int xcd = h & 7, wth = h >> 3;
  const int bid = (xcd < rm ? xcd * (qq + 1) : rm * (qq + 1) + (xcd - rm) * qq) + wth;

  const bool first = (bid < nb0);
  const Job j = first ? j0 : j1;
  const int local = bid - (first ? 0 : nb0);
  const int by = local / j.nbx;
  const int bx = local - by * j.nbx;
  const int m0 = by * 128, n0 = bx * 128;
  const int K = j.K, N = j.N;

  const unsigned short* Abase = (m0 < j.Msplit)
      ? j.Alo + (size_t)m0 * K
      : j.Ahi + (size_t)(m0 - j.Msplit) * K;

  const int tid = threadIdx.x;
  const int l = tid & 63;
  const int w = tid >> 6;
  const int wr = w >> 1, wc = w & 1;
  if (EPI == 2 && tid < 128) colkey[tid] = 0u;

  f32x4 acc[4][4] = {};

  const int srow = w * 32;
  const int lrow = l >> 3;
  const int gcol = ((l & 7) ^ lrow) * 8;   // pre-swizzled global column
  const int mr = l & 15;
  const int kg = l >> 4;

  const int nt = K >> 6;
  const int snap_kb = n0 + wc * 64;
  unsigned short snap[4][4][4];

  auto stage = [&](int buf, int kb) {
#pragma unroll
    for (int i = 0; i < 4; ++i) {
      int r = srow + i * 8;
      gload_lds16(Abase + (size_t)(r + lrow) * K + kb + gcol, &As[buf][r * 64]);
      gload_lds16(j.Bt + (size_t)(n0 + r + lrow) * K + kb + gcol, &Bs[buf][r * 64]);
    }
  };
  auto waitv = [&](int W) {
    if (W >= 2)      asm volatile("s_waitcnt vmcnt(16)\ns_barrier" ::: "memory");
    else if (W == 1) asm volatile("s_waitcnt vmcnt(8)\ns_barrier" ::: "memory");
    else             asm volatile("s_waitcnt vmcnt(0)\ns_barrier" ::: "memory");
  };

  // prologue: up to NBUF tiles in flight; ensure tile 0 landed
#pragma unroll
  for (int p = 0; p < NBUF; ++p) if (p < nt) stage(p, p << 6);
  { int inflight = (NBUF < nt ? NBUF : nt); waitv(inflight - 1); }

  int cur = 0;
  for (int t = 0; t < nt; ++t) {
#pragma unroll
    for (int ks = 0; ks < 2; ++ks) {
      bf8 af[4], bv[4];
#pragma unroll
      for (int mi = 0; mi < 4; ++mi) {
        const int row = wr * 64 + mi * 16 + mr;
        af[mi] = *(const bf8*)&As[cur][row * 64 + (((ks * 4 + kg) ^ (row & 7)) * 8)];
      }
#pragma unroll
      for (int ni = 0; ni < 4; ++ni) {
        const int row = wc * 64 + ni * 16 + mr;
        bv[ni] = *(const bf8*)&Bs[cur][row * 64 + (((ks * 4 + kg) ^ (row & 7)) * 8)];
      }
      __builtin_amdgcn_s_setprio(1);
#pragma unroll
      for (int mi = 0; mi < 4; ++mi)
#pragma unroll
        for (int ni = 0; ni < 4; ++ni)
          acc[mi][ni] = __builtin_amdgcn_mfma_f32_16x16x32_bf16(af[mi], bv[ni], acc[mi][ni], 0, 0, 0);
      __builtin_amdgcn_s_setprio(0);
    }
    if (EPI == 1 && (t << 6) == snap_kb) {
#pragma unroll
      for (int mi = 0; mi < 4; ++mi)
#pragma unroll
        for (int e = 0; e < 4; ++e) {
          const int row = wr * 64 + mi * 16 + kg * 4 + e;
#pragma unroll
          for (int ni = 0; ni < 4; ++ni) {
            const int slot = ni * 2 + (mr >> 3);
            snap[mi][ni][e] = As[cur][row * 64 + ((slot ^ (row & 7)) * 8) + (mr & 7)];
          }
        }
    }
    if (t + 1 < nt) {
      asm volatile("s_waitcnt lgkmcnt(0)\ns_barrier" ::: "memory");   // buf[cur] free everywhere
      if (t + NBUF < nt) stage(cur, (t + NBUF) << 6);                 // refill freed buffer
      int remain = nt - t - 1;                                        // tiles still needed
      int W = (NBUF < remain ? NBUF : remain) - 1;                    // outstanding allowed after wait
      waitv(W);                                                       // tile t+1 landed
      cur = (cur + 1 == NBUF) ? 0 : cur + 1;
    }
  }

  // C/D frag layout: col = mr, row = kg*4 + e (within 16x16)
  const int lr0 = wr * 64;
  const int lc0 = wc * 64;
  if (EPI == 0) {
    unsigned short* Cbase = (m0 < j.Msplit)
        ? j.Clo + (size_t)m0 * N
        : j.Chi + (size_t)(m0 - j.Msplit) * N;
#pragma unroll
    for (int mi = 0; mi < 4; ++mi)
#pragma unroll
      for (int ni = 0; ni < 4; ++ni)
#pragma unroll
        for (int e = 0; e < 4; ++e)
          Cbase[(size_t)(lr0 + mi * 16 + kg * 4 + e) * (size_t)N + (n0 + lc0 + ni * 16 + mr)] = f2bf(acc[mi][ni][e]);
  } else if (EPI == 1) {
    float rp[4][4] = {};
    float bp[4][4] = {};
#pragma unroll
    for (int ni = 0; ni < 4; ++ni) {
      const float bwv = j.bw[n0 + lc0 + ni * 16 + mr];
#pragma unroll
      for (int mi = 0; mi < 4; ++mi)
#pragma unroll
        for (int e = 0; e < 4; ++e) {
          const float av = bf2f(snap[mi][ni][e]);
          rp[mi][e] += acc[mi][ni][e] * av;
          bp[mi][e] += bwv * av;
        }
    }
#pragma unroll
    for (int off = 1; off < 16; off <<= 1)
#pragma unroll
      for (int mi = 0; mi < 4; ++mi)
#pragma unroll
        for (int e = 0; e < 4; ++e) {
          rp[mi][e] += __shfl_xor(rp[mi][e], off);
          bp[mi][e] += __shfl_xor(bp[mi][e], off);
        }
    if (mr == 0) {
      // UNIQUE writer per (column-half slot = bx*2+wc, row) — round-7 race fix.
      const size_t slotbase = (size_t)(bx * 2 + wc) * j.Mtot;
#pragma unroll
      for (int mi = 0; mi < 4; ++mi)
#pragma unroll
        for (int e = 0; e < 4; ++e) {
          const int r = m0 + lr0 + mi * 16 + kg * 4 + e;
          j.pnsq[slotbase + r] = rp[mi][e];
          j.pbwd[slotbase + r] = bp[mi][e];
        }
    }
  } else {
    float nv[4][4];
#pragma unroll
    for (int mi = 0; mi < 4; ++mi)
#pragma unroll
      for (int e = 0; e < 4; ++e)
        nv[mi][e] = j.ninv[m0 + lr0 + mi * 16 + kg * 4 + e];   // one load per element (k_ninv precomputed)
#pragma unroll
    for (int ni = 0; ni < 4; ++ni) {
      float blv = j.bl[n0 + lc0 + ni * 16 + mr];
      float mx = -3.0e38f;
#pragma unroll
      for (int mi = 0; mi < 4; ++mi)
#pragma unroll
        for (int e = 0; e < 4; ++e) mx = fmaxf(mx, (acc[mi][ni][e] + blv) * nv[mi][e]);
      atomicMax(&colkey[lc0 + ni * 16 + mr], fkey(mx));   // LDS atomic only
    }
    __syncthreads();
    if (tid < 128) j.cmax[(size_t)by * 1024 + n0 + tid] = kdec(colkey[tid]);  // unique writer
  }
}

__global__ __launch_bounds__(256) void k_gP (Job a, Job b, int nb0) { gemm_body<0, 3>(a, b, nb0); }
__global__ __launch_bounds__(256) void k_gE1(Job a, Job b, int nb0) { gemm_body<1, 2>(a, b, nb0); }
__global__ __launch_bounds__(256) void k_gE2(Job a, Job b, int nb0) { gemm_body<2, 2>(a, b, nb0); }

// ---------------- fp32 pixel Gram: G2[m][n] = sum_c L[c][m]*R[c][n], 1024x1024, K=256 ----------------
__global__ __launch_bounds__(256) void k_pixgram(const float* __restrict__ L, const float* __restrict__ R,
                                                 float* __restrict__ G2) {
  __shared__ float As[16][32];
  __shared__ float Bs[16][32];
  const int tid = threadIdx.x;
  const int tx = tid & 15, ty = tid >> 4;
  const int m0 = blockIdx.y * 32, n0 = blockIdx.x * 32;
  float acc[2][2] = {};
  for (int kb = 0; kb < 256; kb += 16) {
    __syncthreads();
    {
      int kk = tid >> 5, mm = tid & 31;
      As[kk][mm] = L[(size_t)(kb + kk) * 1024 + m0 + mm];
      Bs[kk][mm] = R[(size_t)(kb + kk) * 1024 + n0 + mm];
      int e2 = tid + 256; int kk2 = e2 >> 5, mm2 = e2 & 31;
      As[kk2][mm2] = L[(size_t)(kb + kk2) * 1024 + m0 + mm2];
      Bs[kk2][mm2] = R[(size_t)(kb + kk2) * 1024 + n0 + mm2];
    }
    __syncthreads();
#pragma unroll
    for (int kk = 0; kk < 16; ++kk) {
      float a0 = As[kk][ty * 2], a1 = As[kk][ty * 2 + 1];
      float b0 = Bs[kk][tx * 2], b1 = Bs[kk][tx * 2 + 1];
      acc[0][0] = fmaf(a0, b0, acc[0][0]); acc[0][1] = fmaf(a0, b1, acc[0][1]);
      acc[1][0] = fmaf(a1, b0, acc[1][0]); acc[1][1] = fmaf(a1, b1, acc[1][1]);
    }
  }
#pragma unroll
  for (int i = 0; i < 2; ++i)
#pragma unroll
    for (int j = 0; j < 2; ++j)
      G2[(size_t)(m0 + ty * 2 + i) * 1024 + (n0 + tx * 2 + j)] = acc[i][j];
}

// ---------------- R3 max/argmax from pixel Gram via masked 9-point diagonal-shift sum ----------------
__global__ __launch_bounds__(256) void k_r3max(const float* __restrict__ G2, const float* __restrict__ scu3,
                                               const float* __restrict__ sclr,
                                               float* __restrict__ s3, int* __restrict__ arg) {
  const int m = blockIdx.x;
  const int mi = m >> 5, mj = m & 31;
  float best = -3.0e38f; int bi = 0;
  for (int n = threadIdx.x; n < 1024; n += 256) {
    const int ni = n >> 5, nj = n & 31;
    float raw = 0.f;
#pragma unroll
    for (int dy = -1; dy <= 1; ++dy) {
#pragma unroll
      for (int dx = -1; dx <= 1; ++dx) {
        bool vm = ((unsigned)(mi + dy) < 32u) && ((unsigned)(mj + dx) < 32u);
        bool vn = ((unsigned)(ni + dy) < 32u) && ((unsigned)(nj + dx) < 32u);
        if (vm && vn) {
          int off = dy * 32 + dx;
          raw += G2[(size_t)(m + off) * 1024 + (n + off)];
        }
      }
    }
    float v = raw * scu3[n];
    if (v > best) { best = v; bi = n; }
  }
  __shared__ float bv[256]; __shared__ int bidx[256];
  bv[threadIdx.x] = best; bidx[threadIdx.x] = bi;
  __syncthreads();
  for (int o = 128; o > 0; o >>= 1) {
    if (threadIdx.x < o) {
      float ov = bv[threadIdx.x + o]; int oi = bidx[threadIdx.x + o];
      if (ov > bv[threadIdx.x] || (ov == bv[threadIdx.x] && oi < bidx[threadIdx.x])) {
        bv[threadIdx.x] = ov; bidx[threadIdx.x] = oi;
      }
    }
    __syncthreads();
  }
  if (threadIdx.x == 0) { s3[m] = bv[0] * sclr[m]; arg[m] = bidx[0]; }
}

// ---------------- fused gather+fold + S1/S2 finalize ----------------
// blocks [0,1024): T3; [1024,3072): T2; [3072,7168): T1; [7168,7176): S1/S2 reduce from cmax
__global__ __launch_bounds__(256) void k_tfold(const float* __restrict__ ref3, const float* __restrict__ ref2,
                                               const float* __restrict__ ref1, const int* __restrict__ arg,
                                               const float* __restrict__ cmax1, const float* __restrict__ cmax2,
                                               float* __restrict__ out) {
  int bid = blockIdx.x;
  if (bid < 1024) {
    int id = bid * 256 + threadIdx.x;
    int c = id >> 10, rem = id & 1023;
    int y = rem >> 5, x = rem & 31;
    float s = 0.f;
#pragma unroll
    for (int ki = 0; ki < 3; ++ki) {
      int i = y + 1 - ki;
      if ((unsigned)i >= 32u) continue;
#pragma unroll
      for (int kj = 0; kj < 3; ++kj) {
        int j = x + 1 - kj;
        if ((unsigned)j >= 32u) continue;
        int n2 = arg[i * 32 + j];
        int rr = (n2 >> 5) + ki - 1, cc = (n2 & 31) + kj - 1;
        if ((unsigned)rr < 32u && (unsigned)cc < 32u) s += ref3[(size_t)c * 1024 + rr * 32 + cc];
      }
    }
    out[3072 + id] = s * (1.f / 9.f);
  } else if (bid < 3072) {
    int id = (bid - 1024) * 256 + threadIdx.x;
    int c = id >> 12, rem = id & 4095;
    int y = rem >> 6, x = rem & 63;
    float s = 0.f;
#pragma unroll
    for (int ki = 0; ki < 6; ++ki) {
      int t = y + 2 - ki;
      if (t < 0 || (t & 1)) continue;
      int i = t >> 1;
      if (i >= 32) continue;
#pragma unroll
      for (int kj = 0; kj < 6; ++kj) {
        int t2 = x + 2 - kj;
        if (t2 < 0 || (t2 & 1)) continue;
        int j = t2 >> 1;
        if (j >= 32) continue;
        int n2 = arg[i * 32 + j];
        int rr = (n2 >> 5) * 2 + ki - 2, cc = (n2 & 31) * 2 + kj - 2;
        if ((unsigned)rr < 64u && (unsigned)cc < 64u) s += ref2[(size_t)c * 4096 + rr * 64 + cc];
      }
    }
    out[265216 + id] = s * (1.f / 9.f);
  } else if (bid < 7168) {
    int id = (bid - 3072) * 256 + threadIdx.x;
    int c = id >> 14, rem = id & 16383;
    int y = rem >> 7, x = rem & 127;
    float s = 0.f;
#pragma unroll
    for (int ki = 0; ki < 12; ++ki) {
      int t = y + 4 - ki;
      if (t < 0 || (t & 3)) continue;
      int i = t >> 2;
      if (i >= 32) continue;
#pragma unroll
      for (int kj = 0; kj < 12; ++kj) {
        int t2 = x + 4 - kj;
        if (t2 < 0 || (t2 & 3)) continue;
        int j = t2 >> 2;
        if (j >= 32) continue;
        int n2 = arg[i * 32 + j];
        int rr = (n2 >> 5) * 4 + ki - 4, cc = (n2 & 31) * 4 + kj - 4;
        if ((unsigned)rr < 128u && (unsigned)cc < 128u) s += ref1[(size_t)c * 16384 + rr * 128 + cc];
      }
    }
    out[789504 + id] = s * (1.f / 9.f);
  } else {
    int t = (bid - 7168) * 256 + threadIdx.x;  // 0..2047
    if (t < 1024) {
      float mx = -3.0e38f;
      for (int rb = 0; rb < 128; ++rb) mx = fmaxf(mx, cmax1[rb * 1024 + t]);
      out[t] = mx;            // S_1
    } else {
      int tt = t - 1024;
      float mx = -3.0e38f;
      for (int rb = 0; rb < 32; ++rb) mx = fmaxf(mx, cmax2[rb * 1024 + tt]);
      out[1024 + tt] = mx;    // S_2
    }
  }
}

// ---------------- workspace layout (bytes) ----------------
// zero-initialized (memset each launch): bw accumulators only
static constexpr size_t OFF_BW2     = 0;                        // 1152 f32
static constexpr size_t OFF_BW1     = 4608;                     // 640 f32
static constexpr size_t ZERO_BYTES  = 7168;
// non-zeroed (all cells uniquely written before read):
static constexpr size_t OFF_BB      = 7168;                     // 2 f32 (pad to 256)
static constexpr size_t OFF_BL2     = 7424;                     // 1024 f32
static constexpr size_t OFF_BL1     = 11520;                    // 1024 f32
static constexpr size_t OFF_SCLR    = 15616;                    // 1024 f32
static constexpr size_t OFF_SCU3    = 19712;                    // 1024 f32
static constexpr size_t OFF_R3ARG   = 23808;                    // 1024 int
static constexpr size_t OFF_PNSQ2   = 27904;                    // f32 [18][4096]
static constexpr size_t OFF_PBWD2   = OFF_PNSQ2 + 294912;       // f32 [18][4096]
static constexpr size_t OFF_PNSQ1   = OFF_PBWD2 + 294912;       // f32 [10][16384]
static constexpr size_t OFF_PBWD1   = OFF_PNSQ1 + 655360;       // f32 [10][16384]
static constexpr size_t OFF_CMAX2   = OFF_PBWD1 + 655360;       // f32 [32][1024]
static constexpr size_t OFF_CMAX1   = OFF_CMAX2 + 131072;       // f32 [128][1024]
static constexpr size_t OFF_NINV2   = OFF_CMAX1 + 524288;       // f32 [4096]
static constexpr size_t OFF_NINV1   = OFF_NINV2 + 16384;        // f32 [16384]
static constexpr size_t OFF_LR3NBT  = OFF_NINV1 + 65536;        // bf16 [1024][2304]
static constexpr size_t OFF_U2B     = OFF_LR3NBT + 4718592;     // bf16 [4096][1152]
static constexpr size_t OFF_U1B     = OFF_U2B    + 9437184;     // bf16 [16384][640]
static constexpr size_t OFF_W1T     = OFF_U1B    + 20971520;    // bf16 [1152][2304]
static constexpr size_t OFF_W2T     = OFF_W1T    + 5308416;     // bf16 [640][2304] (rows 576+ zero)
static constexpr size_t OFF_A2      = OFF_W2T    + 2949120;     // bf16 [1152][1152]
static constexpr size_t OFF_A1      = OFF_A2     + 2654208;     // bf16 [640][640]
static constexpr size_t OFF_M2T     = OFF_A1     + 819200;      // bf16 [1024][1152]
static constexpr size_t OFF_M1T     = OFF_M2T    + 2359296;     // bf16 [1024][640]
static constexpr size_t OFF_G2      = OFF_M1T    + 1310720;     // f32 [1024][1024]

extern "C" void kernel_launch(void* const* d_in, const int* in_sizes, int n_in,
                              void* d_out, int out_size, void* d_ws, size_t ws_size,
                              hipStream_t stream) {
  (void)in_sizes; (void)n_in; (void)out_size; (void)ws_size;
  const float* lrsr3  = (const float*)d_in[0];
  const float* rsr1   = (const float*)d_in[1];
  const float* rsr2   = (const float*)d_in[2];
  const float* rsr3   = (const float*)d_in[3];
  const float* ref1   = (const float*)d_in[4];
  const float* ref2   = (const float*)d_in[5];
  const float* ref3   = (const float*)d_in[6];
  const float* W1     = (const float*)d_in[7];
  const float* b1     = (const float*)d_in[8];
  const float* W2     = (const float*)d_in[9];
  const float* b2     = (const float*)d_in[10];
  float* out = (float*)d_out;
  char* ws = (char*)d_ws;

  float*          bw2     = (float*)(ws + OFF_BW2);
  float*          bw1     = (float*)(ws + OFF_BW1);
  float*          bb      = (float*)(ws + OFF_BB);
  float*          bl2     = (float*)(ws + OFF_BL2);
  float*          bl1     = (float*)(ws + OFF_BL1);
  float*          sclr    = (float*)(ws + OFF_SCLR);
  float*          scu3    = (float*)(ws + OFF_SCU3);
  int*            R3arg   = (int*)(ws + OFF_R3ARG);
  float*          pnsq2   = (float*)(ws + OFF_PNSQ2);
  float*          pbwd2   = (float*)(ws + OFF_PBWD2);
  float*          pnsq1   = (float*)(ws + OFF_PNSQ1);
  float*          pbwd1   = (float*)(ws + OFF_PBWD1);
  float*          cmax2   = (float*)(ws + OFF_CMAX2);
  float*          cmax1   = (float*)(ws + OFF_CMAX1);
  float*          ninv2   = (float*)(ws + OFF_NINV2);
  float*          ninv1   = (float*)(ws + OFF_NINV1);
  unsigned short* lr3nbT  = (unsigned short*)(ws + OFF_LR3NBT);
  unsigned short* U2b     = (unsigned short*)(ws + OFF_U2B);
  unsigned short* U1b     = (unsigned short*)(ws + OFF_U1B);
  unsigned short* W1t     = (unsigned short*)(ws + OFF_W1T);
  unsigned short* W2t     = (unsigned short*)(ws + OFF_W2T);
  unsigned short* A2b     = (unsigned short*)(ws + OFF_A2);
  unsigned short* A1b     = (unsigned short*)(ws + OFF_A1);
  unsigned short* M2tb    = (unsigned short*)(ws + OFF_M2T);
  unsigned short* M1tb    = (unsigned short*)(ws + OFF_M1T);
  float*          G2      = (float*)(ws + OFF_G2);

  hipMemsetAsync(d_ws, 0, ZERO_BYTES, stream);
  // zero pad rows 576..639 of W2t
  hipMemsetAsync(ws + OFF_W2T + (size_t)576 * 2304 * 2, 0, (size_t)64 * 2304 * 2, stream);

  // norms + bias dots + pixel Gram (R3 path, all fp32)
  k_colnorm2<<<2048, 256, 0, stream>>>(lrsr3, rsr3, b1, b2, sclr, scu3, bl2, bl1);
  k_pixgram<<<dim3(32, 32), 256, 0, stream>>>(lrsr3, rsr3, G2);
  k_r3max<<<1024, 256, 0, stream>>>(G2, scu3, sclr, out + 2048, R3arg);

  // unfolds / transposes for the bf16 score paths
  k_pass2_md_bf<<<9216, 256, 0, stream>>>(lrsr3, sclr, lr3nbT);
  k_unfold2<<<59392, 256, 0, stream>>>(rsr2, rsr1, U2b, U1b);
  k_wtrans2<<<dim3(27, 36), 256, 0, stream>>>(W1, W2, W1t, W2t);
  k_bwbb<<<dim3(8, 10), 256, 0, stream>>>(W1, W2, b1, b2, bw2, bw1, bb);

  Job jz = {};

  // P: Gram matrices + M^T, fused across row-concat [Wt ; lr3nbT]
  {
    Job a = jz, b = jz;
    a.Alo = W1t; a.Ahi = lr3nbT; a.Msplit = 1152; a.Bt = W1t;
    a.Clo = A2b; a.Chi = M2tb; a.N = 1152; a.K = 2304; a.nbx = 9;
    b.Alo = W2t; b.Ahi = lr3nbT; b.Msplit = 640; b.Bt = W2t;
    b.Clo = A1b; b.Chi = M1tb; b.N = 640; b.K = 2304; b.nbx = 5;
    k_gP<<<153 + 65, 256, 0, stream>>>(a, b, 153);
  }
  // E1: per-(colblock,half) norm/bw partials via Gram quadratic form (no atomics, unique writers)
  {
    Job a = jz, b = jz;
    a.Alo = U2b; a.Ahi = U2b; a.Msplit = 4096; a.Bt = A2b;
    a.bw = bw2; a.pnsq = pnsq2; a.pbwd = pbwd2; a.Mtot = 4096;
    a.N = 1152; a.K = 1152; a.nbx = 9;
    b.Alo = U1b; b.Ahi = U1b; b.Msplit = 16384; b.Bt = A1b;
    b.bw = bw1; b.pnsq = pnsq1; b.pbwd = pbwd1; b.Mtot = 16384;
    b.N = 640; b.K = 640; b.nbx = 5;
    k_gE1<<<288 + 640, 256, 0, stream>>>(a, b, 288);
  }
  // ninv finalize: one pass over the partials (round-8 lesson: NOT in E2's epilogue)
  k_ninv<<<80, 256, 0, stream>>>(pnsq2, pbwd2, pnsq1, pbwd1, bb, ninv2, ninv1);
  // E2: score max, per-rowblock col-max stores
  {
    Job a = jz, b = jz;
    a.Alo = U2b; a.Ahi = U2b; a.Msplit = 4096; a.Bt = M2tb;
    a.bl = bl2; a.ninv = ninv2; a.cmax = cmax2; a.Mtot = 4096;
    a.N = 1024; a.K = 1152; a.nbx = 8;
    b.Alo = U1b; b.Ahi = U1b; b.Msplit = 16384; b.Bt = M1tb;
    b.bl = bl1; b.ninv = ninv1; b.cmax = cmax1; b.Mtot = 16384;
    b.N = 1024; b.K = 640; b.nbx = 8;
    k_gE2<<<256 + 1024, 256, 0, stream>>>(a, b, 256);
  }

  // transfer + S1/S2 finalize (fused)
  k_tfold<<<7176, 256, 0, stream>>>(ref3, ref2, ref1, R3arg, cmax1, cmax2, out);
}

// Round 10
// 301.370 us; speedup vs baseline: 1.3866x; 1.0990x over previous
//
#include <hip/hip_runtime.h>

typedef short bf8 __attribute__((ext_vector_type(8)));
typedef float f32x4 __attribute__((ext_vector_type(4)));

static __device__ __forceinline__ unsigned short f2bf(float f) {
  unsigned u = __float_as_uint(f);
  unsigned r = u + 0x7FFFu + ((u >> 16) & 1u);
  return (unsigned short)(r >> 16);
}
static __device__ __forceinline__ float bf2f(unsigned short h) {
  return __uint_as_float(((unsigned)h) << 16);
}
// order-preserving float<->u32 key (for LDS atomicMax only)
static __device__ __forceinline__ unsigned fkey(float f) {
  unsigned u = __float_as_uint(f);
  return (u & 0x80000000u) ? ~u : (u | 0x80000000u);
}
static __device__ __forceinline__ float kdec(unsigned k) {
  unsigned u = (k & 0x80000000u) ? (k & 0x7FFFFFFFu) : ~k;
  return __uint_as_float(u);
}

// async global->LDS, 16B per lane. lds dest: wave-uniform base + lane*16.
static __device__ __forceinline__ void gload_lds16(const unsigned short* g, unsigned short* l) {
  __builtin_amdgcn_global_load_lds((const __attribute__((address_space(1))) void*)g,
                                   (__attribute__((address_space(3))) void*)l, 16, 0, 0);
}

// unfold(k=3,pad=1,stride=1) value: row d = (cc*3+ki)*3+kj, col m = i*S+j, src [C][S][S]
static __device__ __forceinline__ float uf3(const float* __restrict__ src, int lgS, int d, int m) {
  const int S = 1 << lgS;
  int cc = d / 9;
  int r9 = d - cc * 9;
  int ki = r9 / 3;
  int kj = r9 - ki * 3;
  int i = (m >> lgS) + ki - 1;
  int j = (m & (S - 1)) + kj - 1;
  if ((unsigned)i >= (unsigned)S || (unsigned)j >= (unsigned)S) return 0.f;
  return src[((size_t)cc << (2 * lgS)) + ((size_t)i << lgS) + j];
}

// ---------------- prep kernels (fused) ----------------

// blocks [0,1024): colnorm+bias-dots of lrsr3 -> sclr, bl2, bl1. blocks [1024,2048): colnorm of rsr3 -> scu3.
__global__ __launch_bounds__(256) void k_colnorm2(const float* __restrict__ lrsr3, const float* __restrict__ rsr3,
                                                  const float* __restrict__ b1, const float* __restrict__ b2,
                                                  float* __restrict__ sclr, float* __restrict__ scu3,
                                                  float* __restrict__ bl2, float* __restrict__ bl1) {
  const bool lr = blockIdx.x < 1024;
  const int m = blockIdx.x & 1023;
  const float* src = lr ? lrsr3 : rsr3;
  float s = 0.f, d1 = 0.f, d2 = 0.f;
  for (int d = threadIdx.x; d < 2304; d += 256) {
    float v = uf3(src, 5, d, m);
    s += v * v; d1 += b1[d] * v; d2 += b2[d] * v;
  }
  __shared__ float r0[256], r1[256], r2[256];
  r0[threadIdx.x] = s; r1[threadIdx.x] = d1; r2[threadIdx.x] = d2;
  __syncthreads();
  for (int o = 128; o > 0; o >>= 1) {
    if (threadIdx.x < o) {
      r0[threadIdx.x] += r0[threadIdx.x + o];
      r1[threadIdx.x] += r1[threadIdx.x + o];
      r2[threadIdx.x] += r2[threadIdx.x + o];
    }
    __syncthreads();
  }
  if (threadIdx.x == 0) {
    float sc = 1.f / fmaxf(sqrtf(r0[0]), 1e-12f);
    if (lr) { sclr[m] = sc; bl2[m] = r1[0] * sc; bl1[m] = r2[0] * sc; }
    else    { scu3[m] = sc; }
  }
}

// normalized unfold, bf16, layout [m][d]
__global__ __launch_bounds__(256) void k_pass2_md_bf(const float* __restrict__ src, const float* __restrict__ scale, unsigned short* __restrict__ out) {
  int id = blockIdx.x * 256 + threadIdx.x;
  int m = id / 2304, d = id - m * 2304;
  out[id] = f2bf(uf3(src, 5, d, m) * scale[m]);
}

// fused unfolds: blocks [0,18432): rsr2 -> U2b [4096][1152]; rest: rsr1 -> U1b [16384][640] (cols 576+ zero)
__global__ __launch_bounds__(256) void k_unfold2(const float* __restrict__ rsr2, const float* __restrict__ rsr1,
                                                 unsigned short* __restrict__ U2b, unsigned short* __restrict__ U1b) {
  int bid = blockIdx.x;
  if (bid < 18432) {
    int id = bid * 256 + threadIdx.x;
    int n = id / 1152, c = id - n * 1152;
    U2b[id] = f2bf(uf3(rsr2, 6, c, n));
  } else {
    int id = (bid - 18432) * 256 + threadIdx.x;
    int n = id / 640, c = id - n * 640;
    float v = (c < 576) ? uf3(rsr1, 7, c, n) : 0.f;
    U1b[id] = f2bf(v);
  }
}

// fused W transposes, LDS-tiled 64x64: blocks x<18 -> W1 (Cw=1152), else W2 (Cw=576)
__global__ __launch_bounds__(256) void k_wtrans2(const float* __restrict__ W1, const float* __restrict__ W2,
                                                 unsigned short* __restrict__ W1t, unsigned short* __restrict__ W2t) {
  __shared__ unsigned short Ls[64][65];
  const float* W; unsigned short* Wt; int Cw, c0;
  if (blockIdx.x < 18) { W = W1; Wt = W1t; Cw = 1152; c0 = blockIdx.x * 64; }
  else                 { W = W2; Wt = W2t; Cw = 576;  c0 = (blockIdx.x - 18) * 64; }
  const int d0 = blockIdx.y * 64;
#pragma unroll
  for (int i = 0; i < 16; ++i) {
    int idx = threadIdx.x + i * 256;
    int r = idx >> 6, c = idx & 63;
    Ls[r][c] = f2bf(W[(size_t)(d0 + r) * Cw + c0 + c]);
  }
  __syncthreads();
#pragma unroll
  for (int i = 0; i < 16; ++i) {
    int idx = threadIdx.x + i * 256;
    int cc = idx >> 6, rr = idx & 63;
    Wt[(size_t)(c0 + cc) * 2304 + d0 + rr] = Ls[rr][cc];
  }
}

// fused bw dots + bb: grid (8,10). y<9: x<5 -> bw2 chunk, x in [5,8) -> bw1 chunk. y==9: x==0 -> bb[0], x==1 -> bb[1].
__global__ __launch_bounds__(256) void k_bwbb(const float* __restrict__ W1, const float* __restrict__ W2,
                                              const float* __restrict__ b1, const float* __restrict__ b2,
                                              float* __restrict__ bw2, float* __restrict__ bw1,
                                              float* __restrict__ bb) {
  if (blockIdx.y == 9) {
    if (blockIdx.x >= 2) return;
    const float* b = blockIdx.x ? b2 : b1;
    float s = 0.f;
    for (int d = threadIdx.x; d < 2304; d += 256) s += b[d] * b[d];
    __shared__ float red[256];
    red[threadIdx.x] = s; __syncthreads();
    for (int o = 128; o > 0; o >>= 1) { if (threadIdx.x < o) red[threadIdx.x] += red[threadIdx.x + o]; __syncthreads(); }
    if (threadIdx.x == 0) bb[blockIdx.x] = red[0];
    return;
  }
  const bool two = blockIdx.x < 5;
  const float* W = two ? W1 : W2;
  const float* b = two ? b1 : b2;
  float* bw = two ? bw2 : bw1;
  const int Cw = two ? 1152 : 576;
  int c = (two ? blockIdx.x : blockIdx.x - 5) * 256 + threadIdx.x;
  if (c >= Cw) return;
  int d0 = blockIdx.y * 256;
  float s = 0.f;
  for (int d = d0; d < d0 + 256; ++d) s += b[d] * W[(size_t)d * Cw + c];
  atomicAdd(&bw[c], s);
}

// ---------------- ninv finalize: sum the E1 partials ONCE per row ----------------
// blocks [0,16): ninv2[4096] from 18 partials. blocks [16,80): ninv1[16384] from 10 partials.
__global__ __launch_bounds__(256) void k_ninv(const float* __restrict__ pnsq2, const float* __restrict__ pbwd2,
                                              const float* __restrict__ pnsq1, const float* __restrict__ pbwd1,
                                              const float* __restrict__ bb,
                                              float* __restrict__ ninv2, float* __restrict__ ninv1) {
  int bid = blockIdx.x;
  if (bid < 16) {
    int i = bid * 256 + threadIdx.x;   // < 4096
    float nsq = 0.f, bwd = 0.f;
#pragma unroll
    for (int p = 0; p < 18; ++p) { nsq += pnsq2[p * 4096 + i]; bwd += pbwd2[p * 4096 + i]; }
    float tq = nsq + 2.f * bwd + bb[0];
    ninv2[i] = 1.f / fmaxf(sqrtf(fmaxf(tq, 0.f)), 1e-12f);
  } else {
    int i = (bid - 16) * 256 + threadIdx.x;  // < 16384
    float nsq = 0.f, bwd = 0.f;
#pragma unroll
    for (int p = 0; p < 10; ++p) { nsq += pnsq1[p * 16384 + i]; bwd += pbwd1[p * 16384 + i]; }
    float tq = nsq + 2.f * bwd + bb[1];
    ninv1[i] = 1.f / fmaxf(sqrtf(fmaxf(tq, 0.f)), 1e-12f);
  }
}

// ---------------- bf16 MFMA GEMM body: 128x128 tile, BK=64, 4 waves, counted-vmcnt, XCD-chunked ----------------
// TN: C[i][j] = sum_k A[i][k]*Bt[j][k].  Two jobs per dispatch (logical id < nb0 -> j0).
// EPI 0: store bf16 C (row-split Clo/Chi at Msplit)
// EPI 1: per-(colblock,wave-half) partials (UNIQUE writer per slot = bx*2+wc)
// EPI 2: cmax[by][j] = max_{i in blk} (C[i][j]+bl[j])*ninv[i]   (ninv precomputed by k_ninv)
struct Job {
  const unsigned short* Alo;
  const unsigned short* Ahi;
  const unsigned short* Bt;
  unsigned short* Clo;
  unsigned short* Chi;
  const float* bl;
  const float* bw;
  const float* ninv;
  float* pnsq;
  float* pbwd;
  float* cmax;
  int Msplit, N, K, nbx, Mtot;
};

template <int EPI, int NBUF>
static __device__ __forceinline__ void gemm_body(const Job& j0, const Job& j1, int nb0) {
  __shared__ __align__(16) unsigned short As[NBUF][128 * 64];
  __shared__ __align__(16) unsigned short Bs[NBUF][128 * 64];
  __shared__ unsigned colkey[128];

  // bijective XCD-chunked swizzle (m204)
  const int nwg = (int)gridDim.x;
  const int h = (int)blockIdx.x;
  const int qq = nwg >> 3, rm = nwg & 7;
  const int xcd = h & 7, wth = h >> 3;
  const int bid = (xcd < rm ? xcd * (qq + 1) : rm * (qq + 1) + (xcd - rm) * qq) + wth;

  const bool first = (bid < nb0);
  const Job j = first ? j0 : j1;
  const int local = bid - (first ? 0 : nb0);
  const int by = local / j.nbx;
  const int bx = local - by * j.nbx;
  const int m0 = by * 128, n0 = bx * 128;
  const int K = j.K, N = j.N;

  const unsigned short* Abase = (m0 < j.Msplit)
      ? j.Alo + (size_t)m0 * K
      : j.Ahi + (size_t)(m0 - j.Msplit) * K;

  const int tid = threadIdx.x;
  const int l = tid & 63;
  const int w = tid >> 6;
  const int wr = w >> 1, wc = w & 1;
  if (EPI == 2 && tid < 128) colkey[tid] = 0u;

  f32x4 acc[4][4] = {};

  const int srow = w * 32;
  const int lrow = l >> 3;
  const int gcol = ((l & 7) ^ lrow) * 8;   // pre-swizzled global column
  const int mr = l & 15;
  const int kg = l >> 4;

  const int nt = K >> 6;
  const int snap_kb = n0 + wc * 64;
  unsigned short snap[4][4][4];

  auto stage = [&](int buf, int kb) {
#pragma unroll
    for (int i = 0; i < 4; ++i) {
      int r = srow + i * 8;
      gload_lds16(Abase + (size_t)(r + lrow) * K + kb + gcol, &As[buf][r * 64]);
      gload_lds16(j.Bt + (size_t)(n0 + r + lrow) * K + kb + gcol, &Bs[buf][r * 64]);
    }
  };
  auto waitv = [&](int W) {
    if (W >= 2)      asm volatile("s_waitcnt vmcnt(16)\ns_barrier" ::: "memory");
    else if (W == 1) asm volatile("s_waitcnt vmcnt(8)\ns_barrier" ::: "memory");
    else             asm volatile("s_waitcnt vmcnt(0)\ns_barrier" ::: "memory");
  };

  // prologue: up to NBUF tiles in flight; ensure tile 0 landed
#pragma unroll
  for (int p = 0; p < NBUF; ++p) if (p < nt) stage(p, p << 6);
  { int inflight = (NBUF < nt ? NBUF : nt); waitv(inflight - 1); }

  int cur = 0;
  for (int t = 0; t < nt; ++t) {
#pragma unroll
    for (int ks = 0; ks < 2; ++ks) {
      bf8 af[4], bv[4];
#pragma unroll
      for (int mi = 0; mi < 4; ++mi) {
        const int row = wr * 64 + mi * 16 + mr;
        af[mi] = *(const bf8*)&As[cur][row * 64 + (((ks * 4 + kg) ^ (row & 7)) * 8)];
      }
#pragma unroll
      for (int ni = 0; ni < 4; ++ni) {
        const int row = wc * 64 + ni * 16 + mr;
        bv[ni] = *(const bf8*)&Bs[cur][row * 64 + (((ks * 4 + kg) ^ (row & 7)) * 8)];
      }
      __builtin_amdgcn_s_setprio(1);
#pragma unroll
      for (int mi = 0; mi < 4; ++mi)
#pragma unroll
        for (int ni = 0; ni < 4; ++ni)
          acc[mi][ni] = __builtin_amdgcn_mfma_f32_16x16x32_bf16(af[mi], bv[ni], acc[mi][ni], 0, 0, 0);
      __builtin_amdgcn_s_setprio(0);
    }
    if (EPI == 1 && (t << 6) == snap_kb) {
#pragma unroll
      for (int mi = 0; mi < 4; ++mi)
#pragma unroll
        for (int e = 0; e < 4; ++e) {
          const int row = wr * 64 + mi * 16 + kg * 4 + e;
#pragma unroll
          for (int ni = 0; ni < 4; ++ni) {
            const int slot = ni * 2 + (mr >> 3);
            snap[mi][ni][e] = As[cur][row * 64 + ((slot ^ (row & 7)) * 8) + (mr & 7)];
          }
        }
    }
    if (t + 1 < nt) {
      asm volatile("s_waitcnt lgkmcnt(0)\ns_barrier" ::: "memory");   // buf[cur] free everywhere
      if (t + NBUF < nt) stage(cur, (t + NBUF) << 6);                 // refill freed buffer
      int remain = nt - t - 1;                                        // tiles still needed
      int W = (NBUF < remain ? NBUF : remain) - 1;                    // outstanding allowed after wait
      waitv(W);                                                       // tile t+1 landed
      cur = (cur + 1 == NBUF) ? 0 : cur + 1;
    }
  }

  // C/D frag layout: col = mr, row = kg*4 + e (within 16x16)
  const int lr0 = wr * 64;
  const int lc0 = wc * 64;
  if (EPI == 0) {
    unsigned short* Cbase = (m0 < j.Msplit)
        ? j.Clo + (size_t)m0 * N
        : j.Chi + (size_t)(m0 - j.Msplit) * N;
#pragma unroll
    for (int mi = 0; mi < 4; ++mi)
#pragma unroll
      for (int ni = 0; ni < 4; ++ni)
#pragma unroll
        for (int e = 0; e < 4; ++e)
          Cbase[(size_t)(lr0 + mi * 16 + kg * 4 + e) * (size_t)N + (n0 + lc0 + ni * 16 + mr)] = f2bf(acc[mi][ni][e]);
  } else if (EPI == 1) {
    float rp[4][4] = {};
    float bp[4][4] = {};
#pragma unroll
    for (int ni = 0; ni < 4; ++ni) {
      const float bwv = j.bw[n0 + lc0 + ni * 16 + mr];
#pragma unroll
      for (int mi = 0; mi < 4; ++mi)
#pragma unroll
        for (int e = 0; e < 4; ++e) {
          const float av = bf2f(snap[mi][ni][e]);
          rp[mi][e] += acc[mi][ni][e] * av;
          bp[mi][e] += bwv * av;
        }
    }
#pragma unroll
    for (int off = 1; off < 16; off <<= 1)
#pragma unroll
      for (int mi = 0; mi < 4; ++mi)
#pragma unroll
        for (int e = 0; e < 4; ++e) {
          rp[mi][e] += __shfl_xor(rp[mi][e], off);
          bp[mi][e] += __shfl_xor(bp[mi][e], off);
        }
    if (mr == 0) {
      // UNIQUE writer per (column-half slot = bx*2+wc, row) — round-7 race fix.
      const size_t slotbase = (size_t)(bx * 2 + wc) * j.Mtot;
#pragma unroll
      for (int mi = 0; mi < 4; ++mi)
#pragma unroll
        for (int e = 0; e < 4; ++e) {
          const int r = m0 + lr0 + mi * 16 + kg * 4 + e;
          j.pnsq[slotbase + r] = rp[mi][e];
          j.pbwd[slotbase + r] = bp[mi][e];
        }
    }
  } else {
    float nv[4][4];
#pragma unroll
    for (int mi = 0; mi < 4; ++mi)
#pragma unroll
      for (int e = 0; e < 4; ++e)
        nv[mi][e] = j.ninv[m0 + lr0 + mi * 16 + kg * 4 + e];   // one load per element (k_ninv precomputed)
#pragma unroll
    for (int ni = 0; ni < 4; ++ni) {
      float blv = j.bl[n0 + lc0 + ni * 16 + mr];
      float mx = -3.0e38f;
#pragma unroll
      for (int mi = 0; mi < 4; ++mi)
#pragma unroll
        for (int e = 0; e < 4; ++e) mx = fmaxf(mx, (acc[mi][ni][e] + blv) * nv[mi][e]);
      atomicMax(&colkey[lc0 + ni * 16 + mr], fkey(mx));   // LDS atomic only
    }
    __syncthreads();
    if (tid < 128) j.cmax[(size_t)by * 1024 + n0 + tid] = kdec(colkey[tid]);  // unique writer
  }
}

__global__ __launch_bounds__(256) void k_gP (Job a, Job b, int nb0) { gemm_body<0, 3>(a, b, nb0); }
__global__ __launch_bounds__(256) void k_gE1(Job a, Job b, int nb0) { gemm_body<1, 2>(a, b, nb0); }
__global__ __launch_bounds__(256) void k_gE2(Job a, Job b, int nb0) { gemm_body<2, 2>(a, b, nb0); }

// ---------------- fp32 pixel Gram: G2[m][n] = sum_c L[c][m]*R[c][n], 1024x1024, K=256 ----------------
__global__ __launch_bounds__(256) void k_pixgram(const float* __restrict__ L, const float* __restrict__ R,
                                                 float* __restrict__ G2) {
  __shared__ float As[16][32];
  __shared__ float Bs[16][32];
  const int tid = threadIdx.x;
  const int tx = tid & 15, ty = tid >> 4;
  const int m0 = blockIdx.y * 32, n0 = blockIdx.x * 32;
  float acc[2][2] = {};
  for (int kb = 0; kb < 256; kb += 16) {
    __syncthreads();
    {
      int kk = tid >> 5, mm = tid & 31;
      As[kk][mm] = L[(size_t)(kb + kk) * 1024 + m0 + mm];
      Bs[kk][mm] = R[(size_t)(kb + kk) * 1024 + n0 + mm];
      int e2 = tid + 256; int kk2 = e2 >> 5, mm2 = e2 & 31;
      As[kk2][mm2] = L[(size_t)(kb + kk2) * 1024 + m0 + mm2];
      Bs[kk2][mm2] = R[(size_t)(kb + kk2) * 1024 + n0 + mm2];
    }
    __syncthreads();
#pragma unroll
    for (int kk = 0; kk < 16; ++kk) {
      float a0 = As[kk][ty * 2], a1 = As[kk][ty * 2 + 1];
      float b0 = Bs[kk][tx * 2], b1 = Bs[kk][tx * 2 + 1];
      acc[0][0] = fmaf(a0, b0, acc[0][0]); acc[0][1] = fmaf(a0, b1, acc[0][1]);
      acc[1][0] = fmaf(a1, b0, acc[1][0]); acc[1][1] = fmaf(a1, b1, acc[1][1]);
    }
  }
#pragma unroll
  for (int i = 0; i < 2; ++i)
#pragma unroll
    for (int j = 0; j < 2; ++j)
      G2[(size_t)(m0 + ty * 2 + i) * 1024 + (n0 + tx * 2 + j)] = acc[i][j];
}

// ---------------- R3 max/argmax from pixel Gram via masked 9-point diagonal-shift sum ----------------
__global__ __launch_bounds__(256) void k_r3max(const float* __restrict__ G2, const float* __restrict__ scu3,
                                               const float* __restrict__ sclr,
                                               float* __restrict__ s3, int* __restrict__ arg) {
  const int m = blockIdx.x;
  const int mi = m >> 5, mj = m & 31;
  float best = -3.0e38f; int bi = 0;
  for (int n = threadIdx.x; n < 1024; n += 256) {
    const int ni = n >> 5, nj = n & 31;
    float raw = 0.f;
#pragma unroll
    for (int dy = -1; dy <= 1; ++dy) {
#pragma unroll
      for (int dx = -1; dx <= 1; ++dx) {
        bool vm = ((unsigned)(mi + dy) < 32u) && ((unsigned)(mj + dx) < 32u);
        bool vn = ((unsigned)(ni + dy) < 32u) && ((unsigned)(nj + dx) < 32u);
        if (vm && vn) {
          int off = dy * 32 + dx;
          raw += G2[(size_t)(m + off) * 1024 + (n + off)];
        }
      }
    }
    float v = raw * scu3[n];
    if (v > best) { best = v; bi = n; }
  }
  __shared__ float bv[256]; __shared__ int bidx[256];
  bv[threadIdx.x] = best; bidx[threadIdx.x] = bi;
  __syncthreads();
  for (int o = 128; o > 0; o >>= 1) {
    if (threadIdx.x < o) {
      float ov = bv[threadIdx.x + o]; int oi = bidx[threadIdx.x + o];
      if (ov > bv[threadIdx.x] || (ov == bv[threadIdx.x] && oi < bidx[threadIdx.x])) {
        bv[threadIdx.x] = ov; bidx[threadIdx.x] = oi;
      }
    }
    __syncthreads();
  }
  if (threadIdx.x == 0) { s3[m] = bv[0] * sclr[m]; arg[m] = bidx[0]; }
}

// ---------------- fused gather+fold (vectorized) + S1/S2 finalize ----------------
// Windows contributing to an output pixel group are contiguous within a window:
//   T1 (stride 4): 4-wide x-group gets one float4 per window, cb=(n2&31)*4-4*dj (all-or-nothing at x4)
//   T2 (stride 2): 2-wide x-group gets one float2 per window
//   T3 (stride 1): no contiguity -> stage 4KB plane + arg in LDS, gather from LDS
// blocks [0,256): T3 (1 ch/block); [256,1280): T2; [1280,2304): T1; [2304,2312): S1/S2 from cmax
__global__ __launch_bounds__(256) void k_tfold(const float* __restrict__ ref3, const float* __restrict__ ref2,
                                               const float* __restrict__ ref1, const int* __restrict__ arg,
                                               const float* __restrict__ cmax1, const float* __restrict__ cmax2,
                                               float* __restrict__ out) {
  const int bid = blockIdx.x;
  const int tid = threadIdx.x;
  if (bid < 256) {
    // T3: one channel per block; plane + arg in LDS
    __shared__ float plane[1024];
    __shared__ int argL[1024];
    const int c = bid;
#pragma unroll
    for (int k = 0; k < 4; ++k) {
      plane[k * 256 + tid] = ref3[(size_t)c * 1024 + k * 256 + tid];
      argL[k * 256 + tid] = arg[k * 256 + tid];
    }
    __syncthreads();
#pragma unroll
    for (int k = 0; k < 4; ++k) {
      int px = k * 256 + tid;
      int y = px >> 5, x = px & 31;
      float s = 0.f;
#pragma unroll
      for (int di = -1; di <= 1; ++di) {
        int i = y + di;
        if ((unsigned)i >= 32u) continue;
#pragma unroll
        for (int dj = -1; dj <= 1; ++dj) {
          int jw = x + dj;
          if ((unsigned)jw >= 32u) continue;
          int n2 = argL[i * 32 + jw];
          int rr = (n2 >> 5) + y - i, cc = (n2 & 31) + x - jw;
          if ((unsigned)rr < 32u && (unsigned)cc < 32u) s += plane[rr * 32 + cc];
        }
      }
      out[3072 + (size_t)c * 1024 + px] = s * (1.f / 9.f);
    }
  } else if (bid < 1280) {
    // T2: float2 per thread. id2 -> (c, y, q): x = 2q + e
    __shared__ int argL[1024];
#pragma unroll
    for (int k = 0; k < 4; ++k) argL[k * 256 + tid] = arg[k * 256 + tid];
    __syncthreads();
    int id2 = (bid - 256) * 256 + tid;
    int q = id2 & 31, y = (id2 >> 5) & 63, c = id2 >> 11;
    int iy = y >> 1;
    float s0 = 0.f, s1 = 0.f;
#pragma unroll
    for (int di = -1; di <= 1; ++di) {
      int i = iy + di;
      if ((unsigned)i >= 32u) continue;
      int ry = y - 2 * i;                    // rr = (n2>>5)*2 + ry
#pragma unroll
      for (int dj = -1; dj <= 1; ++dj) {
        int jw = q + dj;
        if ((unsigned)jw >= 32u) continue;
        int n2 = argL[i * 32 + jw];
        int rr = (n2 >> 5) * 2 + ry;
        int cb = (n2 & 31) * 2 + 2 * (q - jw);
        if ((unsigned)rr < 64u && (unsigned)cb < 63u) {
          const float* p = ref2 + (size_t)c * 4096 + rr * 64 + cb;
          s0 += p[0]; s1 += p[1];
        }
      }
    }
    float2 o; o.x = s0 * (1.f / 9.f); o.y = s1 * (1.f / 9.f);
    *(float2*)(out + 265216 + (size_t)c * 4096 + y * 64 + 2 * q) = o;
  } else if (bid < 2304) {
    // T1: float4 per thread. id1 -> (c, y, q): x = 4q + e
    __shared__ int argL[1024];
#pragma unroll
    for (int k = 0; k < 4; ++k) argL[k * 256 + tid] = arg[k * 256 + tid];
    __syncthreads();
    int id1 = (bid - 1280) * 256 + tid;
    int q = id1 & 31, y = (id1 >> 5) & 127, c = id1 >> 12;
    int iy = y >> 2;
    f32x4 s = {0.f, 0.f, 0.f, 0.f};
#pragma unroll
    for (int di = -1; di <= 1; ++di) {
      int i = iy + di;
      if ((unsigned)i >= 32u) continue;
      int ry = y - 4 * i;                    // rr = (n2>>5)*4 + ry
#pragma unroll
      for (int dj = -1; dj <= 1; ++dj) {
        int jw = q + dj;
        if ((unsigned)jw >= 32u) continue;
        int n2 = argL[i * 32 + jw];
        int rr = (n2 >> 5) * 4 + ry;
        int cb = (n2 & 31) * 4 + 4 * (q - jw);
        if ((unsigned)rr < 128u && (unsigned)cb < 125u) {
          f32x4 v = *(const f32x4*)(ref1 + (size_t)c * 16384 + rr * 128 + cb);
          s += v;
        }
      }
    }
    s *= (1.f / 9.f);
    *(f32x4*)(out + 789504 + (size_t)c * 16384 + y * 128 + 4 * q) = s;
  } else {
    int t = (bid - 2304) * 256 + tid;  // 0..2047
    if (t < 1024) {
      float mx = -3.0e38f;
      for (int rb = 0; rb < 128; ++rb) mx = fmaxf(mx, cmax1[rb * 1024 + t]);
      out[t] = mx;            // S_1
    } else {
      int tt = t - 1024;
      float mx = -3.0e38f;
      for (int rb = 0; rb < 32; ++rb) mx = fmaxf(mx, cmax2[rb * 1024 + tt]);
      out[1024 + tt] = mx;    // S_2
    }
  }
}

// ---------------- workspace layout (bytes) ----------------
// zero-initialized (memset each launch): bw accumulators only
static constexpr size_t OFF_BW2     = 0;                        // 1152 f32
static constexpr size_t OFF_BW1     = 4608;                     // 640 f32
static constexpr size_t ZERO_BYTES  = 7168;
// non-zeroed (all cells uniquely written before read):
static constexpr size_t OFF_BB      = 7168;                     // 2 f32 (pad to 256)
static constexpr size_t OFF_BL2     = 7424;                     // 1024 f32
static constexpr size_t OFF_BL1     = 11520;                    // 1024 f32
static constexpr size_t OFF_SCLR    = 15616;                    // 1024 f32
static constexpr size_t OFF_SCU3    = 19712;                    // 1024 f32
static constexpr size_t OFF_R3ARG   = 23808;                    // 1024 int
static constexpr size_t OFF_PNSQ2   = 27904;                    // f32 [18][4096]
static constexpr size_t OFF_PBWD2   = OFF_PNSQ2 + 294912;       // f32 [18][4096]
static constexpr size_t OFF_PNSQ1   = OFF_PBWD2 + 294912;       // f32 [10][16384]
static constexpr size_t OFF_PBWD1   = OFF_PNSQ1 + 655360;       // f32 [10][16384]
static constexpr size_t OFF_CMAX2   = OFF_PBWD1 + 655360;       // f32 [32][1024]
static constexpr size_t OFF_CMAX1   = OFF_CMAX2 + 131072;       // f32 [128][1024]
static constexpr size_t OFF_NINV2   = OFF_CMAX1 + 524288;       // f32 [4096]
static constexpr size_t OFF_NINV1   = OFF_NINV2 + 16384;        // f32 [16384]
static constexpr size_t OFF_LR3NBT  = OFF_NINV1 + 65536;        // bf16 [1024][2304]
static constexpr size_t OFF_U2B     = OFF_LR3NBT + 4718592;     // bf16 [4096][1152]
static constexpr size_t OFF_U1B     = OFF_U2B    + 9437184;     // bf16 [16384][640]
static constexpr size_t OFF_W1T     = OFF_U1B    + 20971520;    // bf16 [1152][2304]
static constexpr size_t OFF_W2T     = OFF_W1T    + 5308416;     // bf16 [640][2304] (rows 576+ zero)
static constexpr size_t OFF_A2      = OFF_W2T    + 2949120;     // bf16 [1152][1152]
static constexpr size_t OFF_A1      = OFF_A2     + 2654208;     // bf16 [640][640]
static constexpr size_t OFF_M2T     = OFF_A1     + 819200;      // bf16 [1024][1152]
static constexpr size_t OFF_M1T     = OFF_M2T    + 2359296;     // bf16 [1024][640]
static constexpr size_t OFF_G2      = OFF_M1T    + 1310720;     // f32 [1024][1024]

extern "C" void kernel_launch(void* const* d_in, const int* in_sizes, int n_in,
                              void* d_out, int out_size, void* d_ws, size_t ws_size,
                              hipStream_t stream) {
  (void)in_sizes; (void)n_in; (void)out_size; (void)ws_size;
  const float* lrsr3  = (const float*)d_in[0];
  const float* rsr1   = (const float*)d_in[1];
  const float* rsr2   = (const float*)d_in[2];
  const float* rsr3   = (const float*)d_in[3];
  const float* ref1   = (const float*)d_in[4];
  const float* ref2   = (const float*)d_in[5];
  const float* ref3   = (const float*)d_in[6];
  const float* W1     = (const float*)d_in[7];
  const float* b1     = (const float*)d_in[8];
  const float* W2     = (const float*)d_in[9];
  const float* b2     = (const float*)d_in[10];
  float* out = (float*)d_out;
  char* ws = (char*)d_ws;

  float*          bw2     = (float*)(ws + OFF_BW2);
  float*          bw1     = (float*)(ws + OFF_BW1);
  float*          bb      = (float*)(ws + OFF_BB);
  float*          bl2     = (float*)(ws + OFF_BL2);
  float*          bl1     = (float*)(ws + OFF_BL1);
  float*          sclr    = (float*)(ws + OFF_SCLR);
  float*          scu3    = (float*)(ws + OFF_SCU3);
  int*            R3arg   = (int*)(ws + OFF_R3ARG);
  float*          pnsq2   = (float*)(ws + OFF_PNSQ2);
  float*          pbwd2   = (float*)(ws + OFF_PBWD2);
  float*          pnsq1   = (float*)(ws + OFF_PNSQ1);
  float*          pbwd1   = (float*)(ws + OFF_PBWD1);
  float*          cmax2   = (float*)(ws + OFF_CMAX2);
  float*          cmax1   = (float*)(ws + OFF_CMAX1);
  float*          ninv2   = (float*)(ws + OFF_NINV2);
  float*          ninv1   = (float*)(ws + OFF_NINV1);
  unsigned short* lr3nbT  = (unsigned short*)(ws + OFF_LR3NBT);
  unsigned short* U2b     = (unsigned short*)(ws + OFF_U2B);
  unsigned short* U1b     = (unsigned short*)(ws + OFF_U1B);
  unsigned short* W1t     = (unsigned short*)(ws + OFF_W1T);
  unsigned short* W2t     = (unsigned short*)(ws + OFF_W2T);
  unsigned short* A2b     = (unsigned short*)(ws + OFF_A2);
  unsigned short* A1b     = (unsigned short*)(ws + OFF_A1);
  unsigned short* M2tb    = (unsigned short*)(ws + OFF_M2T);
  unsigned short* M1tb    = (unsigned short*)(ws + OFF_M1T);
  float*          G2      = (float*)(ws + OFF_G2);

  hipMemsetAsync(d_ws, 0, ZERO_BYTES, stream);
  // zero pad rows 576..639 of W2t
  hipMemsetAsync(ws + OFF_W2T + (size_t)576 * 2304 * 2, 0, (size_t)64 * 2304 * 2, stream);

  // norms + bias dots + pixel Gram (R3 path, all fp32)
  k_colnorm2<<<2048, 256, 0, stream>>>(lrsr3, rsr3, b1, b2, sclr, scu3, bl2, bl1);
  k_pixgram<<<dim3(32, 32), 256, 0, stream>>>(lrsr3, rsr3, G2);
  k_r3max<<<1024, 256, 0, stream>>>(G2, scu3, sclr, out + 2048, R3arg);

  // unfolds / transposes for the bf16 score paths
  k_pass2_md_bf<<<9216, 256, 0, stream>>>(lrsr3, sclr, lr3nbT);
  k_unfold2<<<59392, 256, 0, stream>>>(rsr2, rsr1, U2b, U1b);
  k_wtrans2<<<dim3(27, 36), 256, 0, stream>>>(W1, W2, W1t, W2t);
  k_bwbb<<<dim3(8, 10), 256, 0, stream>>>(W1, W2, b1, b2, bw2, bw1, bb);

  Job jz = {};

  // P: Gram matrices + M^T, fused across row-concat [Wt ; lr3nbT]
  {
    Job a = jz, b = jz;
    a.Alo = W1t; a.Ahi = lr3nbT; a.Msplit = 1152; a.Bt = W1t;
    a.Clo = A2b; a.Chi = M2tb; a.N = 1152; a.K = 2304; a.nbx = 9;
    b.Alo = W2t; b.Ahi = lr3nbT; b.Msplit = 640; b.Bt = W2t;
    b.Clo = A1b; b.Chi = M1tb; b.N = 640; b.K = 2304; b.nbx = 5;
    k_gP<<<153 + 65, 256, 0, stream>>>(a, b, 153);
  }
  // E1: per-(colblock,half) norm/bw partials via Gram quadratic form (no atomics, unique writers)
  {
    Job a = jz, b = jz;
    a.Alo = U2b; a.Ahi = U2b; a.Msplit = 4096; a.Bt = A2b;
    a.bw = bw2; a.pnsq = pnsq2; a.pbwd = pbwd2; a.Mtot = 4096;
    a.N = 1152; a.K = 1152; a.nbx = 9;
    b.Alo = U1b; b.Ahi = U1b; b.Msplit = 16384; b.Bt = A1b;
    b.bw = bw1; b.pnsq = pnsq1; b.pbwd = pbwd1; b.Mtot = 16384;
    b.N = 640; b.K = 640; b.nbx = 5;
    k_gE1<<<288 + 640, 256, 0, stream>>>(a, b, 288);
  }
  // ninv finalize: one pass over the partials
  k_ninv<<<80, 256, 0, stream>>>(pnsq2, pbwd2, pnsq1, pbwd1, bb, ninv2, ninv1);
  // E2: score max, per-rowblock col-max stores
  {
    Job a = jz, b = jz;
    a.Alo = U2b; a.Ahi = U2b; a.Msplit = 4096; a.Bt = M2tb;
    a.bl = bl2; a.ninv = ninv2; a.cmax = cmax2; a.Mtot = 4096;
    a.N = 1024; a.K = 1152; a.nbx = 8;
    b.Alo = U1b; b.Ahi = U1b; b.Msplit = 16384; b.Bt = M1tb;
    b.bl = bl1; b.ninv = ninv1; b.cmax = cmax1; b.Mtot = 16384;
    b.N = 1024; b.K = 640; b.nbx = 8;
    k_gE2<<<256 + 1024, 256, 0, stream>>>(a, b, 256);
  }

  // transfer + S1/S2 finalize (fused, vectorized gathers)
  k_tfold<<<2312, 256, 0, stream>>>(ref3, ref2, ref1, R3arg, cmax1, cmax2, out);
}